// Round 2
// baseline (320.931 us; speedup 1.0000x reference)
//
#include <hip/hip_runtime.h>
#include <hip/hip_bf16.h>
#include <stdint.h>
#include <math.h>

// Problem: B=4, S=2048, D=1024 causal self-attention, f32 I/O.
// out = [output (4,2048,1024) | attn_weights (4,2048,2048)] flat f32.
// Strategy: convert X,W to bf16 once; all GEMMs use 16x16x32 bf16 MFMA
// (128x128 tile, m97-style global_load_lds staging); raw f32 scores go
// directly into the attn-weights region of d_out and are softmaxed in
// place (also emitting a bf16 P copy into ws for the P.Vt GEMM).
//
// ws layout (bytes):
//   [0 .. 16M)  Q  (bf16)        -- dead after scores; aliased by Pb
//   [16M..32M)  K  (bf16)        -- dead after scores; aliased by Pb
//   [32M..48M)  Vt (bf16, per-batch [D][S])
//   [48M..64M)  Xb (bf16)
//   [64M..70M)  Wqb|Wkb|Wvb (bf16, 2MB each)
//   Pb (bf16, 32MB) aliases [0..32M) -- written by softmax after Q,K die.

typedef __hip_bfloat16 bf16;
typedef __attribute__((ext_vector_type(8))) short short8;
typedef __attribute__((ext_vector_type(4))) float f32x4;

#define BM 128
#define BN 128
#define BK 32

static constexpr int Bb = 4;
static constexpr int S  = 2048;
static constexpr int D  = 1024;
static constexpr size_t QK_ELEMS = (size_t)Bb * S * D;   // 8388608
static constexpr size_t SS_ELEMS = (size_t)S * S;        // 4194304 per batch
static constexpr size_t W_ELEMS  = (size_t)D * D;        // 1048576

__device__ __forceinline__ void async16(const bf16* g, bf16* l) {
  __builtin_amdgcn_global_load_lds(
      (__attribute__((address_space(1))) const void*)g,
      (__attribute__((address_space(3))) void*)l, 16, 0, 0);
}

// C[m,n] += sum_k A[m,k]*B[n,k]  (NT GEMM), 128x128 tile, 4 waves, 16x16x32.
// SWAP=true computes the transposed tile (output rows indexed by B rows).
template<bool SWAP>
__device__ __forceinline__ void gemm_core(const bf16* __restrict__ A,
                                          const bf16* __restrict__ B,
                                          int ldA, int ldB, int ksteps,
                                          bf16* As, bf16* Bs,
                                          f32x4 acc[4][4])
{
  const int tid  = threadIdx.x;
  const int lane = tid & 63;
  const int wave = tid >> 6;
  const int wm   = (wave & 1) * 64;
  const int wn   = (wave >> 1) * 64;
  const int m16  = lane & 15;
  const int kq   = lane >> 4;

  // staging: 512 x 16B chunks per tile, 2 per thread; LDS dest must be
  // wave-uniform base + lane*16 -> chunk index c = i*256 + tid.
  const int c0 = tid,        c1 = tid + 256;
  const int r0 = c0 >> 2;    const int f0 = (c0 & 3) * 8;
  const int r1 = c1 >> 2;    const int f1 = (c1 & 3) * 8;

  for (int ks = 0; ks < ksteps; ++ks) {
    const int k = ks * BK;
    async16(A + (size_t)r0 * ldA + k + f0, As + (size_t)c0 * 8);
    async16(A + (size_t)r1 * ldA + k + f1, As + (size_t)c1 * 8);
    async16(B + (size_t)r0 * ldB + k + f0, Bs + (size_t)c0 * 8);
    async16(B + (size_t)r1 * ldB + k + f1, Bs + (size_t)c1 * 8);
    __syncthreads();

    short8 af[4], bfrag[4];
    #pragma unroll
    for (int i = 0; i < 4; ++i)
      af[i] = *(const short8*)&As[(wm + i * 16 + m16) * BK + kq * 8];
    #pragma unroll
    for (int i = 0; i < 4; ++i)
      bfrag[i] = *(const short8*)&Bs[(wn + i * 16 + m16) * BK + kq * 8];

    #pragma unroll
    for (int mi = 0; mi < 4; ++mi) {
      #pragma unroll
      for (int ni = 0; ni < 4; ++ni) {
        if (SWAP)
          acc[mi][ni] = __builtin_amdgcn_mfma_f32_16x16x32_bf16(
              bfrag[ni], af[mi], acc[mi][ni], 0, 0, 0);
        else
          acc[mi][ni] = __builtin_amdgcn_mfma_f32_16x16x32_bf16(
              af[mi], bfrag[ni], acc[mi][ni], 0, 0, 0);
      }
    }
    __syncthreads();
  }
}

__device__ __forceinline__ void zero_acc(f32x4 acc[4][4]) {
  #pragma unroll
  for (int mi = 0; mi < 4; ++mi)
    #pragma unroll
    for (int ni = 0; ni < 4; ++ni)
      acc[mi][ni] = (f32x4){0.f, 0.f, 0.f, 0.f};
}

// ---- Stage 0: f32 -> bf16 conversion of X, Wq, Wk, Wv --------------------
__device__ __forceinline__ unsigned short f2b(float f) {
  __hip_bfloat16 h = __float2bfloat16(f);
  return *(unsigned short*)&h;
}

__global__ __launch_bounds__(256)
void cvt_kernel(const float* __restrict__ X,  const float* __restrict__ Wq,
                const float* __restrict__ Wk, const float* __restrict__ Wv,
                bf16* __restrict__ Xb, bf16* __restrict__ Wqb,
                bf16* __restrict__ Wkb, bf16* __restrict__ Wvb)
{
  const size_t g = ((size_t)blockIdx.x * 256 + threadIdx.x) * 4;
  const float* src; bf16* dst; size_t off;
  if (g < QK_ELEMS) { src = X; dst = Xb; off = g; }
  else {
    const size_t h = g - QK_ELEMS;
    const int w = (int)(h >> 20);
    off = h & (W_ELEMS - 1);
    src = (w == 0) ? Wq : (w == 1) ? Wk : Wv;
    dst = (w == 0) ? Wqb : (w == 1) ? Wkb : Wvb;
  }
  const float4 v = *(const float4*)(src + off);
  uint2 o;
  o.x = (uint32_t)f2b(v.x) | ((uint32_t)f2b(v.y) << 16);
  o.y = (uint32_t)f2b(v.z) | ((uint32_t)f2b(v.w) << 16);
  *(uint2*)((unsigned short*)dst + off) = o;
}

// ---- Stage A1: Q = Xb Wq^T, K = Xb Wk^T (bf16 out) -----------------------
__global__ __launch_bounds__(256, 2)
void qk_kernel(const bf16* __restrict__ X, const bf16* __restrict__ Wq,
               const bf16* __restrict__ Wk, bf16* __restrict__ Q,
               bf16* __restrict__ Ko)
{
  __shared__ __align__(16) bf16 As[BM * BK];
  __shared__ __align__(16) bf16 Bs[BN * BK];
  const int nt = blockIdx.x, mt = blockIdx.y, z = blockIdx.z;
  const bf16* W = z ? Wk : Wq;
  bf16* Out = z ? Ko : Q;

  f32x4 acc[4][4];
  zero_acc(acc);
  gemm_core<false>(X + (size_t)mt * 128 * D, W + (size_t)nt * 128 * D,
                   D, D, D / BK, As, Bs, acc);

  const int lane = threadIdx.x & 63, wave = threadIdx.x >> 6;
  const int wm = (wave & 1) * 64, wn = (wave >> 1) * 64;
  const int col0 = lane & 15, row0 = (lane >> 4) * 4;
  #pragma unroll
  for (int mi = 0; mi < 4; ++mi)
    #pragma unroll
    for (int ni = 0; ni < 4; ++ni)
      #pragma unroll
      for (int r = 0; r < 4; ++r) {
        const int grow = mt * 128 + wm + mi * 16 + row0 + r;
        const int gcol = nt * 128 + wn + ni * 16 + col0;
        Out[(size_t)grow * D + gcol] = __float2bfloat16(acc[mi][ni][r]);
      }
}

// ---- Stage A2: Vt[b][e][s] = (Xb Wv^T)^T ---------------------------------
__global__ __launch_bounds__(256, 2)
void vt_kernel(const bf16* __restrict__ X, const bf16* __restrict__ Wv,
               bf16* __restrict__ Vt)
{
  __shared__ __align__(16) bf16 As[BM * BK];
  __shared__ __align__(16) bf16 Bs[BN * BK];
  const int nt = blockIdx.x, mt = blockIdx.y;

  f32x4 acc[4][4];
  zero_acc(acc);
  gemm_core<true>(X + (size_t)mt * 128 * D, Wv + (size_t)nt * 128 * D,
                  D, D, D / BK, As, Bs, acc);

  const int lane = threadIdx.x & 63, wave = threadIdx.x >> 6;
  const int wm = (wave & 1) * 64, wn = (wave >> 1) * 64;
  const int col0 = lane & 15, row0 = (lane >> 4) * 4;
  const int b = (mt * 128) >> 11;          // batch of this s-block
  #pragma unroll
  for (int mi = 0; mi < 4; ++mi)
    #pragma unroll
    for (int ni = 0; ni < 4; ++ni)
      #pragma unroll
      for (int r = 0; r < 4; ++r) {
        const int ge = nt * 128 + wn + ni * 16 + row0 + r;      // d index
        const int gs = mt * 128 + wm + mi * 16 + col0;          // s global
        const int sl = gs & (S - 1);
        Vt[(size_t)b * D * S + (size_t)ge * S + sl] = __float2bfloat16(acc[mi][ni][r]);
      }
}

// ---- Stage B: Sc = Q K^T / 32 -> f32, straight into d_out attn region ----
__global__ __launch_bounds__(256, 2)
void scores_kernel(const bf16* __restrict__ Q, const bf16* __restrict__ K,
                   float* __restrict__ Sc)
{
  const int kt = blockIdx.x, qt = blockIdx.y, b = blockIdx.z;
  if (kt > qt) return;                      // causal tile skip
  __shared__ __align__(16) bf16 As[BM * BK];
  __shared__ __align__(16) bf16 Bs[BN * BK];

  f32x4 acc[4][4];
  zero_acc(acc);
  gemm_core<false>(Q + ((size_t)b * S + qt * 128) * D,
                   K + ((size_t)b * S + kt * 128) * D,
                   D, D, D / BK, As, Bs, acc);

  const int lane = threadIdx.x & 63, wave = threadIdx.x >> 6;
  const int wm = (wave & 1) * 64, wn = (wave >> 1) * 64;
  const int col0 = lane & 15, row0 = (lane >> 4) * 4;
  float* out = Sc + (size_t)b * SS_ELEMS;
  #pragma unroll
  for (int mi = 0; mi < 4; ++mi)
    #pragma unroll
    for (int ni = 0; ni < 4; ++ni)
      #pragma unroll
      for (int r = 0; r < 4; ++r) {
        const int gq = qt * 128 + wm + mi * 16 + row0 + r;
        const int gk = kt * 128 + wn + ni * 16 + col0;
        out[(size_t)gq * S + gk] = acc[mi][ni][r] * 0.03125f;
      }
}

// ---- Stage C: causal row softmax in place (f32) + bf16 P copy ------------
__device__ __forceinline__ float wave_max(float v) {
  #pragma unroll
  for (int o = 32; o > 0; o >>= 1) v = fmaxf(v, __shfl_xor(v, o, 64));
  return v;
}
__device__ __forceinline__ float wave_sum(float v) {
  #pragma unroll
  for (int o = 32; o > 0; o >>= 1) v += __shfl_xor(v, o, 64);
  return v;
}

__global__ __launch_bounds__(256)
void softmax_kernel(float* __restrict__ Attn, bf16* __restrict__ Pb)
{
  const int row = blockIdx.x;            // 0..8191
  const int b = row >> 11, i = row & (S - 1);
  float* s = Attn + (size_t)b * SS_ELEMS + (size_t)i * S;   // read+rewrite
  bf16* p  = Pb   + (size_t)b * SS_ELEMS + (size_t)i * S;
  const int t = threadIdx.x;
  const int lane = t & 63, wave = t >> 6;
  __shared__ float red[4];

  float vals[8];
  #pragma unroll
  for (int u = 0; u < 8; ++u) {
    const int j = t + u * 256;
    vals[u] = (j <= i) ? s[j] : -INFINITY;
  }
  float m = -INFINITY;
  #pragma unroll
  for (int u = 0; u < 8; ++u) m = fmaxf(m, vals[u]);
  m = wave_max(m);
  if (lane == 0) red[wave] = m;
  __syncthreads();
  m = fmaxf(fmaxf(red[0], red[1]), fmaxf(red[2], red[3]));
  __syncthreads();

  float sum = 0.f;
  #pragma unroll
  for (int u = 0; u < 8; ++u) {
    const float e = expf(vals[u] - m);   // expf(-inf)=0 handles masked
    vals[u] = e;
    sum += e;
  }
  sum = wave_sum(sum);
  if (lane == 0) red[wave] = sum;
  __syncthreads();
  sum = red[0] + red[1] + red[2] + red[3];
  const float inv = 1.f / sum;           // sum >= 1 (j=i term is exp(0))

  #pragma unroll
  for (int u = 0; u < 8; ++u) {
    const int j = t + u * 256;
    const float w = vals[u] * inv;
    s[j] = w;                            // f32 attn weights (exact output)
    p[j] = __float2bfloat16(w);          // bf16 copy for the PV GEMM
  }
}

// ---- Stage D: O = P Vt^T (causal K-truncation), f32 out ------------------
__global__ __launch_bounds__(256, 2)
void out_kernel(const bf16* __restrict__ P, const bf16* __restrict__ Vt,
                float* __restrict__ O)
{
  const int dt = blockIdx.x, qt = blockIdx.y, b = blockIdx.z;
  __shared__ __align__(16) bf16 As[BM * BK];
  __shared__ __align__(16) bf16 Bs[BN * BK];

  f32x4 acc[4][4];
  zero_acc(acc);
  const int ksteps = (qt + 1) * (128 / BK);   // only k <= q-block end nonzero
  gemm_core<false>(P + (size_t)b * SS_ELEMS + (size_t)qt * 128 * S,
                   Vt + (size_t)b * D * S + (size_t)dt * 128 * S,
                   S, S, ksteps, As, Bs, acc);

  const int lane = threadIdx.x & 63, wave = threadIdx.x >> 6;
  const int wm = (wave & 1) * 64, wn = (wave >> 1) * 64;
  const int col0 = lane & 15, row0 = (lane >> 4) * 4;
  #pragma unroll
  for (int mi = 0; mi < 4; ++mi)
    #pragma unroll
    for (int ni = 0; ni < 4; ++ni)
      #pragma unroll
      for (int r = 0; r < 4; ++r) {
        const int gq = qt * 128 + wm + mi * 16 + row0 + r;
        const int gd = dt * 128 + wn + ni * 16 + col0;
        O[((size_t)b * S + gq) * D + gd] = acc[mi][ni][r];
      }
}

extern "C" void kernel_launch(void* const* d_in, const int* in_sizes, int n_in,
                              void* d_out, int out_size, void* d_ws, size_t ws_size,
                              hipStream_t stream) {
  const float* X  = (const float*)d_in[0];
  // d_in[1] = causal mask (int32 tril) — applied analytically, not read.
  const float* Wq = (const float*)d_in[2];
  const float* Wk = (const float*)d_in[3];
  const float* Wv = (const float*)d_in[4];

  float* Out  = (float*)d_out;               // (4,2048,1024) f32
  float* Attn = Out + QK_ELEMS;              // (4,2048,2048) f32

  bf16* Q   = (bf16*)d_ws;                   // 16MB
  bf16* K   = Q + QK_ELEMS;                  // 16MB
  bf16* Vt  = K + QK_ELEMS;                  // 16MB
  bf16* Xb  = Vt + QK_ELEMS;                 // 16MB
  bf16* Wqb = Xb + QK_ELEMS;                 // 2MB
  bf16* Wkb = Wqb + W_ELEMS;                 // 2MB
  bf16* Wvb = Wkb + W_ELEMS;                 // 2MB  -> ws total 70MB
  bf16* Pb  = (bf16*)d_ws;                   // 32MB, aliases Q+K (dead by then)

  const int cvt_blocks = (int)((QK_ELEMS + 3 * W_ELEMS) / 4 / 256);
  cvt_kernel<<<cvt_blocks, 256, 0, stream>>>(X, Wq, Wk, Wv, Xb, Wqb, Wkb, Wvb);
  qk_kernel<<<dim3(D / 128, (Bb * S) / 128, 2), 256, 0, stream>>>(Xb, Wqb, Wkb, Q, K);
  vt_kernel<<<dim3(D / 128, (Bb * S) / 128, 1), 256, 0, stream>>>(Xb, Wvb, Vt);
  scores_kernel<<<dim3(S / 128, S / 128, Bb), 256, 0, stream>>>(Q, K, Attn);
  softmax_kernel<<<dim3(Bb * S), 256, 0, stream>>>(Attn, Pb);
  out_kernel<<<dim3(D / 128, S / 128, Bb), 256, 0, stream>>>(Pb, Vt, Out);
}

// Round 3
// 315.730 us; speedup vs baseline: 1.0165x; 1.0165x over previous
//
#include <hip/hip_runtime.h>
#include <hip/hip_bf16.h>
#include <stdint.h>
#include <math.h>

// B=4, S=2048, D=1024 causal self-attention, f32 I/O.
// out = [output (4,2048,1024) | attn_weights (4,2048,2048)] flat f32.
// Pipeline: cvt(f32->bf16) -> fused QKV GEMM (Q,K row-major; V transposed)
// -> causal-tile scores GEMM (f32 into d_out attn region) -> in-place row
// softmax (+bf16 P copy) -> P.Vt GEMM (causal K-truncation, heavy-first).
//
// ws layout: Q(16M) K(16M) Vt(16M) Xb(16M) Wq|Wk|Wv b16 (6M); Pb(32M)
// aliases Q+K after they die.

typedef __hip_bfloat16 bf16;
typedef __attribute__((ext_vector_type(8))) short short8;
typedef __attribute__((ext_vector_type(4))) float f32x4;

#define BM 128
#define BN 128
#define BK 32

static constexpr int Bb = 4;
static constexpr int S  = 2048;
static constexpr int D  = 1024;
static constexpr size_t QK_ELEMS = (size_t)Bb * S * D;   // 8388608
static constexpr size_t SS_ELEMS = (size_t)S * S;        // 4194304 per batch
static constexpr size_t W_ELEMS  = (size_t)D * D;        // 1048576

__device__ __forceinline__ void async16(const bf16* g, bf16* l) {
  __builtin_amdgcn_global_load_lds(
      (__attribute__((address_space(1))) const void*)g,
      (__attribute__((address_space(3))) void*)l, 16, 0, 0);
}

// C[m,n] += sum_k A[m,k]*B[n,k]  (NT GEMM), 128x128 tile, 4 waves, 16x16x32.
// SWAP=true computes the transposed tile (output rows indexed by B rows).
template<bool SWAP>
__device__ __forceinline__ void gemm_core(const bf16* __restrict__ A,
                                          const bf16* __restrict__ B,
                                          int ldA, int ldB, int ksteps,
                                          bf16* As, bf16* Bs,
                                          f32x4 acc[4][4])
{
  const int tid  = threadIdx.x;
  const int lane = tid & 63;
  const int wave = tid >> 6;
  const int wm   = (wave & 1) * 64;
  const int wn   = (wave >> 1) * 64;
  const int m16  = lane & 15;
  const int kq   = lane >> 4;

  const int c0 = tid,        c1 = tid + 256;
  const int r0 = c0 >> 2;    const int f0 = (c0 & 3) * 8;
  const int r1 = c1 >> 2;    const int f1 = (c1 & 3) * 8;

  for (int ks = 0; ks < ksteps; ++ks) {
    const int k = ks * BK;
    async16(A + (size_t)r0 * ldA + k + f0, As + (size_t)c0 * 8);
    async16(A + (size_t)r1 * ldA + k + f1, As + (size_t)c1 * 8);
    async16(B + (size_t)r0 * ldB + k + f0, Bs + (size_t)c0 * 8);
    async16(B + (size_t)r1 * ldB + k + f1, Bs + (size_t)c1 * 8);
    __syncthreads();

    short8 af[4], bfrag[4];
    #pragma unroll
    for (int i = 0; i < 4; ++i)
      af[i] = *(const short8*)&As[(wm + i * 16 + m16) * BK + kq * 8];
    #pragma unroll
    for (int i = 0; i < 4; ++i)
      bfrag[i] = *(const short8*)&Bs[(wn + i * 16 + m16) * BK + kq * 8];

    #pragma unroll
    for (int mi = 0; mi < 4; ++mi) {
      #pragma unroll
      for (int ni = 0; ni < 4; ++ni) {
        if (SWAP)
          acc[mi][ni] = __builtin_amdgcn_mfma_f32_16x16x32_bf16(
              bfrag[ni], af[mi], acc[mi][ni], 0, 0, 0);
        else
          acc[mi][ni] = __builtin_amdgcn_mfma_f32_16x16x32_bf16(
              af[mi], bfrag[ni], acc[mi][ni], 0, 0, 0);
      }
    }
    __syncthreads();
  }
}

__device__ __forceinline__ void zero_acc(f32x4 acc[4][4]) {
  #pragma unroll
  for (int mi = 0; mi < 4; ++mi)
    #pragma unroll
    for (int ni = 0; ni < 4; ++ni)
      acc[mi][ni] = (f32x4){0.f, 0.f, 0.f, 0.f};
}

// ---- Stage 0: f32 -> bf16 conversion of X, Wq, Wk, Wv --------------------
__device__ __forceinline__ unsigned short f2b(float f) {
  __hip_bfloat16 h = __float2bfloat16(f);
  return *(unsigned short*)&h;
}

__global__ __launch_bounds__(256)
void cvt_kernel(const float* __restrict__ X,  const float* __restrict__ Wq,
                const float* __restrict__ Wk, const float* __restrict__ Wv,
                bf16* __restrict__ Xb, bf16* __restrict__ Wqb,
                bf16* __restrict__ Wkb, bf16* __restrict__ Wvb)
{
  const size_t g = ((size_t)blockIdx.x * 256 + threadIdx.x) * 4;
  const float* src; bf16* dst; size_t off;
  if (g < QK_ELEMS) { src = X; dst = Xb; off = g; }
  else {
    const size_t h = g - QK_ELEMS;
    const int w = (int)(h >> 20);
    off = h & (W_ELEMS - 1);
    src = (w == 0) ? Wq : (w == 1) ? Wk : Wv;
    dst = (w == 0) ? Wqb : (w == 1) ? Wkb : Wvb;
  }
  const float4 v = *(const float4*)(src + off);
  uint2 o;
  o.x = (uint32_t)f2b(v.x) | ((uint32_t)f2b(v.y) << 16);
  o.y = (uint32_t)f2b(v.z) | ((uint32_t)f2b(v.w) << 16);
  *(uint2*)((unsigned short*)dst + off) = o;
}

// ---- Stage A: fused QKV. z=0: Q, z=1: K (row-major); z=2: Vt (transposed)
__global__ __launch_bounds__(256, 3)
void qkv_kernel(const bf16* __restrict__ X, const bf16* __restrict__ Wq,
                const bf16* __restrict__ Wk, const bf16* __restrict__ Wv,
                bf16* __restrict__ Q, bf16* __restrict__ Ko,
                bf16* __restrict__ Vt)
{
  __shared__ __align__(16) bf16 As[BM * BK];
  __shared__ __align__(16) bf16 Bs[BN * BK];
  const int nt = blockIdx.x, mt = blockIdx.y, z = blockIdx.z;
  const bf16* W = (z == 0) ? Wq : (z == 1) ? Wk : Wv;

  const int lane = threadIdx.x & 63, wave = threadIdx.x >> 6;
  const int wm = (wave & 1) * 64, wn = (wave >> 1) * 64;
  const int col0 = lane & 15, row0 = (lane >> 4) * 4;

  f32x4 acc[4][4];
  zero_acc(acc);
  if (z < 2) {
    gemm_core<false>(X + (size_t)mt * 128 * D, W + (size_t)nt * 128 * D,
                     D, D, D / BK, As, Bs, acc);
    bf16* Out = z ? Ko : Q;
    #pragma unroll
    for (int mi = 0; mi < 4; ++mi)
      #pragma unroll
      for (int ni = 0; ni < 4; ++ni)
        #pragma unroll
        for (int r = 0; r < 4; ++r) {
          const int grow = mt * 128 + wm + mi * 16 + row0 + r;
          const int gcol = nt * 128 + wn + ni * 16 + col0;
          Out[(size_t)grow * D + gcol] = __float2bfloat16(acc[mi][ni][r]);
        }
  } else {
    gemm_core<true>(X + (size_t)mt * 128 * D, W + (size_t)nt * 128 * D,
                    D, D, D / BK, As, Bs, acc);
    const int b = (mt * 128) >> 11;
    #pragma unroll
    for (int mi = 0; mi < 4; ++mi)
      #pragma unroll
      for (int ni = 0; ni < 4; ++ni)
        #pragma unroll
        for (int r = 0; r < 4; ++r) {
          const int ge = nt * 128 + wn + ni * 16 + row0 + r;      // d index
          const int gs = mt * 128 + wm + mi * 16 + col0;          // s global
          const int sl = gs & (S - 1);
          Vt[(size_t)b * D * S + (size_t)ge * S + sl] = __float2bfloat16(acc[mi][ni][r]);
        }
  }
}

// ---- Stage B: Sc = Q K^T / 32 -> f32 into d_out attn region --------------
// Flattened lower-triangle tile grid: 136 tiles/batch, zero dead blocks.
__global__ __launch_bounds__(256, 3)
void scores_kernel(const bf16* __restrict__ Q, const bf16* __restrict__ K,
                   float* __restrict__ Sc)
{
  const int t = blockIdx.x, b = blockIdx.y;
  // decode t -> (qt, kt), kt <= qt, t = qt(qt+1)/2 + kt
  int qt = (int)((sqrtf(8.f * (float)t + 1.f) - 1.f) * 0.5f);
  while ((qt + 1) * (qt + 2) / 2 <= t) ++qt;
  while (qt * (qt + 1) / 2 > t) --qt;
  const int kt = t - qt * (qt + 1) / 2;

  __shared__ __align__(16) bf16 As[BM * BK];
  __shared__ __align__(16) bf16 Bs[BN * BK];

  f32x4 acc[4][4];
  zero_acc(acc);
  gemm_core<false>(Q + ((size_t)b * S + qt * 128) * D,
                   K + ((size_t)b * S + kt * 128) * D,
                   D, D, D / BK, As, Bs, acc);

  const int lane = threadIdx.x & 63, wave = threadIdx.x >> 6;
  const int wm = (wave & 1) * 64, wn = (wave >> 1) * 64;
  const int col0 = lane & 15, row0 = (lane >> 4) * 4;
  float* out = Sc + (size_t)b * SS_ELEMS;
  #pragma unroll
  for (int mi = 0; mi < 4; ++mi)
    #pragma unroll
    for (int ni = 0; ni < 4; ++ni)
      #pragma unroll
      for (int r = 0; r < 4; ++r) {
        const int gq = qt * 128 + wm + mi * 16 + row0 + r;
        const int gk = kt * 128 + wn + ni * 16 + col0;
        out[(size_t)gq * S + gk] = acc[mi][ni][r] * 0.03125f;
      }
}

// ---- Stage C: causal row softmax in place (f32) + bf16 P copy ------------
__device__ __forceinline__ float wave_max(float v) {
  #pragma unroll
  for (int o = 32; o > 0; o >>= 1) v = fmaxf(v, __shfl_xor(v, o, 64));
  return v;
}
__device__ __forceinline__ float wave_sum(float v) {
  #pragma unroll
  for (int o = 32; o > 0; o >>= 1) v += __shfl_xor(v, o, 64);
  return v;
}

__global__ __launch_bounds__(256)
void softmax_kernel(float* __restrict__ Attn, bf16* __restrict__ Pb)
{
  const int row = blockIdx.x;            // 0..8191
  const int b = row >> 11, i = row & (S - 1);
  float* s = Attn + (size_t)b * SS_ELEMS + (size_t)i * S;
  bf16* p  = Pb   + (size_t)b * SS_ELEMS + (size_t)i * S;
  const int t = threadIdx.x;
  const int lane = t & 63, wave = t >> 6;
  __shared__ float red[4];

  float vals[8];
  #pragma unroll
  for (int u = 0; u < 8; ++u) {
    const int j = t + u * 256;
    vals[u] = (j <= i) ? s[j] : -INFINITY;
  }
  float m = -INFINITY;
  #pragma unroll
  for (int u = 0; u < 8; ++u) m = fmaxf(m, vals[u]);
  m = wave_max(m);
  if (lane == 0) red[wave] = m;
  __syncthreads();
  m = fmaxf(fmaxf(red[0], red[1]), fmaxf(red[2], red[3]));
  __syncthreads();

  float sum = 0.f;
  #pragma unroll
  for (int u = 0; u < 8; ++u) {
    const float e = expf(vals[u] - m);   // expf(-inf)=0 handles masked
    vals[u] = e;
    sum += e;
  }
  sum = wave_sum(sum);
  if (lane == 0) red[wave] = sum;
  __syncthreads();
  sum = red[0] + red[1] + red[2] + red[3];
  const float inv = 1.f / sum;           // sum >= 1 (diag term is exp(0))

  #pragma unroll
  for (int u = 0; u < 8; ++u) {
    const int j = t + u * 256;
    const float w = vals[u] * inv;
    s[j] = w;                            // f32 attn weights (exact output)
    p[j] = __float2bfloat16(w);          // bf16 copy for the PV GEMM
  }
}

// ---- Stage D: O = P Vt^T (causal K-truncation), heavy qt first -----------
__global__ __launch_bounds__(256, 3)
void out_kernel(const bf16* __restrict__ P, const bf16* __restrict__ Vt,
                float* __restrict__ O)
{
  const int dt = blockIdx.x, qt = (S / 128 - 1) - blockIdx.y, b = blockIdx.z;
  __shared__ __align__(16) bf16 As[BM * BK];
  __shared__ __align__(16) bf16 Bs[BN * BK];

  f32x4 acc[4][4];
  zero_acc(acc);
  const int ksteps = (qt + 1) * (128 / BK);   // only k <= q-block end nonzero
  gemm_core<false>(P + (size_t)b * SS_ELEMS + (size_t)qt * 128 * S,
                   Vt + (size_t)b * D * S + (size_t)dt * 128 * S,
                   S, S, ksteps, As, Bs, acc);

  const int lane = threadIdx.x & 63, wave = threadIdx.x >> 6;
  const int wm = (wave & 1) * 64, wn = (wave >> 1) * 64;
  const int col0 = lane & 15, row0 = (lane >> 4) * 4;
  #pragma unroll
  for (int mi = 0; mi < 4; ++mi)
    #pragma unroll
    for (int ni = 0; ni < 4; ++ni)
      #pragma unroll
      for (int r = 0; r < 4; ++r) {
        const int gq = qt * 128 + wm + mi * 16 + row0 + r;
        const int gd = dt * 128 + wn + ni * 16 + col0;
        O[((size_t)b * S + gq) * D + gd] = acc[mi][ni][r];
      }
}

extern "C" void kernel_launch(void* const* d_in, const int* in_sizes, int n_in,
                              void* d_out, int out_size, void* d_ws, size_t ws_size,
                              hipStream_t stream) {
  const float* X  = (const float*)d_in[0];
  // d_in[1] = causal mask (int32 tril) — applied analytically, not read.
  const float* Wq = (const float*)d_in[2];
  const float* Wk = (const float*)d_in[3];
  const float* Wv = (const float*)d_in[4];

  float* Out  = (float*)d_out;               // (4,2048,1024) f32
  float* Attn = Out + QK_ELEMS;              // (4,2048,2048) f32

  bf16* Q   = (bf16*)d_ws;                   // 16MB
  bf16* K   = Q + QK_ELEMS;                  // 16MB
  bf16* Vt  = K + QK_ELEMS;                  // 16MB
  bf16* Xb  = Vt + QK_ELEMS;                 // 16MB
  bf16* Wqb = Xb + QK_ELEMS;                 // 2MB
  bf16* Wkb = Wqb + W_ELEMS;                 // 2MB
  bf16* Wvb = Wkb + W_ELEMS;                 // 2MB  -> ws total 70MB
  bf16* Pb  = (bf16*)d_ws;                   // 32MB, aliases Q+K (dead by then)

  const int cvt_blocks = (int)((QK_ELEMS + 3 * W_ELEMS) / 4 / 256);
  cvt_kernel<<<cvt_blocks, 256, 0, stream>>>(X, Wq, Wk, Wv, Xb, Wqb, Wkb, Wvb);
  qkv_kernel<<<dim3(D / 128, (Bb * S) / 128, 3), 256, 0, stream>>>(
      Xb, Wqb, Wkb, Wvb, Q, K, Vt);
  const int ntile = (S / 128) * (S / 128 + 1) / 2;   // 136
  scores_kernel<<<dim3(ntile, Bb), 256, 0, stream>>>(Q, K, Attn);
  softmax_kernel<<<dim3(Bb * S), 256, 0, stream>>>(Attn, Pb);
  out_kernel<<<dim3(D / 128, S / 128, Bb), 256, 0, stream>>>(Pb, Vt, Out);
}

// Round 4
// 312.904 us; speedup vs baseline: 1.0257x; 1.0090x over previous
//
#include <hip/hip_runtime.h>
#include <hip/hip_bf16.h>
#include <stdint.h>
#include <math.h>

// B=4, S=2048, D=1024 causal self-attention, f32 I/O.
// out = [output (4,2048,1024) | attn_weights (4,2048,2048)] flat f32.
// Pipeline: cvt(f32->bf16) -> fused QKV GEMM (Q,K row-major; V transposed)
// -> causal-tile scores GEMM (f32 into d_out attn region) -> in-place row
// softmax (+bf16 P copy) -> P.Vt GEMM (causal K-truncation, heavy-first).
// R3->R4: BK 32->64 (half the barrier drains per K-loop, 32 MFMA/barrier).

typedef __hip_bfloat16 bf16;
typedef __attribute__((ext_vector_type(8))) short short8;
typedef __attribute__((ext_vector_type(4))) float f32x4;

#define BM 128
#define BN 128
#define BK 64

static constexpr int Bb = 4;
static constexpr int S  = 2048;
static constexpr int D  = 1024;
static constexpr size_t QK_ELEMS = (size_t)Bb * S * D;   // 8388608
static constexpr size_t SS_ELEMS = (size_t)S * S;        // 4194304 per batch
static constexpr size_t W_ELEMS  = (size_t)D * D;        // 1048576

__device__ __forceinline__ void async16(const bf16* g, bf16* l) {
  __builtin_amdgcn_global_load_lds(
      (__attribute__((address_space(1))) const void*)g,
      (__attribute__((address_space(3))) void*)l, 16, 0, 0);
}

// C[m,n] += sum_k A[m,k]*B[n,k]  (NT GEMM), 128x128 tile, BK=64, 4 waves,
// 16x16x32 bf16 MFMA. SWAP=true computes the transposed tile.
template<bool SWAP>
__device__ __forceinline__ void gemm_core(const bf16* __restrict__ A,
                                          const bf16* __restrict__ B,
                                          int ldA, int ldB, int ksteps,
                                          bf16* As, bf16* Bs,
                                          f32x4 acc[4][4])
{
  const int tid  = threadIdx.x;
  const int lane = tid & 63;
  const int wave = tid >> 6;
  const int wm   = (wave & 1) * 64;
  const int wn   = (wave >> 1) * 64;
  const int m16  = lane & 15;
  const int kq   = lane >> 4;

  // tile = 128 rows x 64 elems = 1024 x 16B chunks; 4 per thread.
  // chunk c = i*256 + tid -> row r = c>>3, elem offset f = (c&7)*8.
  // LDS dest = c*16B (wave-uniform base + lane*16 within each (i,wave)).
  int r[4], f[4];
  #pragma unroll
  for (int i = 0; i < 4; ++i) {
    const int c = tid + i * 256;
    r[i] = c >> 3;
    f[i] = (c & 7) * 8;
  }

  for (int ks = 0; ks < ksteps; ++ks) {
    const int k = ks * BK;
    #pragma unroll
    for (int i = 0; i < 4; ++i)
      async16(A + (size_t)r[i] * ldA + k + f[i], As + ((size_t)tid + i * 256) * 8);
    #pragma unroll
    for (int i = 0; i < 4; ++i)
      async16(B + (size_t)r[i] * ldB + k + f[i], Bs + ((size_t)tid + i * 256) * 8);
    __syncthreads();

    #pragma unroll
    for (int j = 0; j < 2; ++j) {
      short8 af[4], bfr[4];
      #pragma unroll
      for (int i = 0; i < 4; ++i)
        af[i] = *(const short8*)&As[(wm + i * 16 + m16) * BK + j * 32 + kq * 8];
      #pragma unroll
      for (int i = 0; i < 4; ++i)
        bfr[i] = *(const short8*)&Bs[(wn + i * 16 + m16) * BK + j * 32 + kq * 8];

      #pragma unroll
      for (int mi = 0; mi < 4; ++mi) {
        #pragma unroll
        for (int ni = 0; ni < 4; ++ni) {
          if (SWAP)
            acc[mi][ni] = __builtin_amdgcn_mfma_f32_16x16x32_bf16(
                bfr[ni], af[mi], acc[mi][ni], 0, 0, 0);
          else
            acc[mi][ni] = __builtin_amdgcn_mfma_f32_16x16x32_bf16(
                af[mi], bfr[ni], acc[mi][ni], 0, 0, 0);
        }
      }
    }
    __syncthreads();
  }
}

__device__ __forceinline__ void zero_acc(f32x4 acc[4][4]) {
  #pragma unroll
  for (int mi = 0; mi < 4; ++mi)
    #pragma unroll
    for (int ni = 0; ni < 4; ++ni)
      acc[mi][ni] = (f32x4){0.f, 0.f, 0.f, 0.f};
}

// ---- Stage 0: f32 -> bf16 conversion of X, Wq, Wk, Wv --------------------
__device__ __forceinline__ unsigned short f2b(float f) {
  __hip_bfloat16 h = __float2bfloat16(f);
  return *(unsigned short*)&h;
}

__global__ __launch_bounds__(256)
void cvt_kernel(const float* __restrict__ X,  const float* __restrict__ Wq,
                const float* __restrict__ Wk, const float* __restrict__ Wv,
                bf16* __restrict__ Xb, bf16* __restrict__ Wqb,
                bf16* __restrict__ Wkb, bf16* __restrict__ Wvb)
{
  const size_t g = ((size_t)blockIdx.x * 256 + threadIdx.x) * 4;
  const float* src; bf16* dst; size_t off;
  if (g < QK_ELEMS) { src = X; dst = Xb; off = g; }
  else {
    const size_t h = g - QK_ELEMS;
    const int w = (int)(h >> 20);
    off = h & (W_ELEMS - 1);
    src = (w == 0) ? Wq : (w == 1) ? Wk : Wv;
    dst = (w == 0) ? Wqb : (w == 1) ? Wkb : Wvb;
  }
  const float4 v = *(const float4*)(src + off);
  uint2 o;
  o.x = (uint32_t)f2b(v.x) | ((uint32_t)f2b(v.y) << 16);
  o.y = (uint32_t)f2b(v.z) | ((uint32_t)f2b(v.w) << 16);
  *(uint2*)((unsigned short*)dst + off) = o;
}

// ---- Stage A: fused QKV. z=0: Q, z=1: K (row-major); z=2: Vt (transposed)
__global__ __launch_bounds__(256, 3)
void qkv_kernel(const bf16* __restrict__ X, const bf16* __restrict__ Wq,
                const bf16* __restrict__ Wk, const bf16* __restrict__ Wv,
                bf16* __restrict__ Q, bf16* __restrict__ Ko,
                bf16* __restrict__ Vt)
{
  __shared__ __align__(16) bf16 As[BM * BK];
  __shared__ __align__(16) bf16 Bs[BN * BK];
  const int nt = blockIdx.x, mt = blockIdx.y, z = blockIdx.z;
  const bf16* W = (z == 0) ? Wq : (z == 1) ? Wk : Wv;

  const int lane = threadIdx.x & 63, wave = threadIdx.x >> 6;
  const int wm = (wave & 1) * 64, wn = (wave >> 1) * 64;
  const int col0 = lane & 15, row0 = (lane >> 4) * 4;

  f32x4 acc[4][4];
  zero_acc(acc);
  if (z < 2) {
    gemm_core<false>(X + (size_t)mt * 128 * D, W + (size_t)nt * 128 * D,
                     D, D, D / BK, As, Bs, acc);
    bf16* Out = z ? Ko : Q;
    #pragma unroll
    for (int mi = 0; mi < 4; ++mi)
      #pragma unroll
      for (int ni = 0; ni < 4; ++ni)
        #pragma unroll
        for (int r = 0; r < 4; ++r) {
          const int grow = mt * 128 + wm + mi * 16 + row0 + r;
          const int gcol = nt * 128 + wn + ni * 16 + col0;
          Out[(size_t)grow * D + gcol] = __float2bfloat16(acc[mi][ni][r]);
        }
  } else {
    gemm_core<true>(X + (size_t)mt * 128 * D, W + (size_t)nt * 128 * D,
                    D, D, D / BK, As, Bs, acc);
    const int b = (mt * 128) >> 11;
    #pragma unroll
    for (int mi = 0; mi < 4; ++mi)
      #pragma unroll
      for (int ni = 0; ni < 4; ++ni)
        #pragma unroll
        for (int r = 0; r < 4; ++r) {
          const int ge = nt * 128 + wn + ni * 16 + row0 + r;      // d index
          const int gs = mt * 128 + wm + mi * 16 + col0;          // s global
          const int sl = gs & (S - 1);
          Vt[(size_t)b * D * S + (size_t)ge * S + sl] = __float2bfloat16(acc[mi][ni][r]);
        }
  }
}

// ---- Stage B: Sc = Q K^T / 32 -> f32 into d_out attn region --------------
// Flattened lower-triangle tile grid: 136 tiles/batch, zero dead blocks.
__global__ __launch_bounds__(256, 3)
void scores_kernel(const bf16* __restrict__ Q, const bf16* __restrict__ K,
                   float* __restrict__ Sc)
{
  const int t = blockIdx.x, b = blockIdx.y;
  int qt = (int)((sqrtf(8.f * (float)t + 1.f) - 1.f) * 0.5f);
  while ((qt + 1) * (qt + 2) / 2 <= t) ++qt;
  while (qt * (qt + 1) / 2 > t) --qt;
  const int kt = t - qt * (qt + 1) / 2;

  __shared__ __align__(16) bf16 As[BM * BK];
  __shared__ __align__(16) bf16 Bs[BN * BK];

  f32x4 acc[4][4];
  zero_acc(acc);
  gemm_core<false>(Q + ((size_t)b * S + qt * 128) * D,
                   K + ((size_t)b * S + kt * 128) * D,
                   D, D, D / BK, As, Bs, acc);

  const int lane = threadIdx.x & 63, wave = threadIdx.x >> 6;
  const int wm = (wave & 1) * 64, wn = (wave >> 1) * 64;
  const int col0 = lane & 15, row0 = (lane >> 4) * 4;
  float* out = Sc + (size_t)b * SS_ELEMS;
  #pragma unroll
  for (int mi = 0; mi < 4; ++mi)
    #pragma unroll
    for (int ni = 0; ni < 4; ++ni)
      #pragma unroll
      for (int r = 0; r < 4; ++r) {
        const int gq = qt * 128 + wm + mi * 16 + row0 + r;
        const int gk = kt * 128 + wn + ni * 16 + col0;
        out[(size_t)gq * S + gk] = acc[mi][ni][r] * 0.03125f;
      }
}

// ---- Stage C: causal row softmax in place (f32) + bf16 P copy ------------
__device__ __forceinline__ float wave_max(float v) {
  #pragma unroll
  for (int o = 32; o > 0; o >>= 1) v = fmaxf(v, __shfl_xor(v, o, 64));
  return v;
}
__device__ __forceinline__ float wave_sum(float v) {
  #pragma unroll
  for (int o = 32; o > 0; o >>= 1) v += __shfl_xor(v, o, 64);
  return v;
}

__global__ __launch_bounds__(256)
void softmax_kernel(float* __restrict__ Attn, bf16* __restrict__ Pb)
{
  const int row = blockIdx.x;            // 0..8191
  const int b = row >> 11, i = row & (S - 1);
  float* s = Attn + (size_t)b * SS_ELEMS + (size_t)i * S;
  bf16* p  = Pb   + (size_t)b * SS_ELEMS + (size_t)i * S;
  const int t = threadIdx.x;
  const int lane = t & 63, wave = t >> 6;
  __shared__ float red[4];

  float vals[8];
  #pragma unroll
  for (int u = 0; u < 8; ++u) {
    const int j = t + u * 256;
    vals[u] = (j <= i) ? s[j] : -INFINITY;
  }
  float m = -INFINITY;
  #pragma unroll
  for (int u = 0; u < 8; ++u) m = fmaxf(m, vals[u]);
  m = wave_max(m);
  if (lane == 0) red[wave] = m;
  __syncthreads();
  m = fmaxf(fmaxf(red[0], red[1]), fmaxf(red[2], red[3]));
  __syncthreads();

  float sum = 0.f;
  #pragma unroll
  for (int u = 0; u < 8; ++u) {
    const float e = expf(vals[u] - m);   // expf(-inf)=0 handles masked
    vals[u] = e;
    sum += e;
  }
  sum = wave_sum(sum);
  if (lane == 0) red[wave] = sum;
  __syncthreads();
  sum = red[0] + red[1] + red[2] + red[3];
  const float inv = 1.f / sum;           // sum >= 1 (diag term is exp(0))

  #pragma unroll
  for (int u = 0; u < 8; ++u) {
    const int j = t + u * 256;
    const float w = vals[u] * inv;
    s[j] = w;                            // f32 attn weights (exact output)
    p[j] = __float2bfloat16(w);          // bf16 copy for the PV GEMM
  }
}

// ---- Stage D: O = P Vt^T (causal K-truncation), heavy qt first -----------
__global__ __launch_bounds__(256, 3)
void out_kernel(const bf16* __restrict__ P, const bf16* __restrict__ Vt,
                float* __restrict__ O)
{
  const int dt = blockIdx.x, qt = (S / 128 - 1) - blockIdx.y, b = blockIdx.z;
  __shared__ __align__(16) bf16 As[BM * BK];
  __shared__ __align__(16) bf16 Bs[BN * BK];

  f32x4 acc[4][4];
  zero_acc(acc);
  const int ksteps = (qt + 1) * (128 / BK);   // only k <= q-block end nonzero
  gemm_core<false>(P + (size_t)b * SS_ELEMS + (size_t)qt * 128 * S,
                   Vt + (size_t)b * D * S + (size_t)dt * 128 * S,
                   S, S, ksteps, As, Bs, acc);

  const int lane = threadIdx.x & 63, wave = threadIdx.x >> 6;
  const int wm = (wave & 1) * 64, wn = (wave >> 1) * 64;
  const int col0 = lane & 15, row0 = (lane >> 4) * 4;
  #pragma unroll
  for (int mi = 0; mi < 4; ++mi)
    #pragma unroll
    for (int ni = 0; ni < 4; ++ni)
      #pragma unroll
      for (int r = 0; r < 4; ++r) {
        const int gq = qt * 128 + wm + mi * 16 + row0 + r;
        const int gd = dt * 128 + wn + ni * 16 + col0;
        O[((size_t)b * S + gq) * D + gd] = acc[mi][ni][r];
      }
}

extern "C" void kernel_launch(void* const* d_in, const int* in_sizes, int n_in,
                              void* d_out, int out_size, void* d_ws, size_t ws_size,
                              hipStream_t stream) {
  const float* X  = (const float*)d_in[0];
  // d_in[1] = causal mask (int32 tril) — applied analytically, not read.
  const float* Wq = (const float*)d_in[2];
  const float* Wk = (const float*)d_in[3];
  const float* Wv = (const float*)d_in[4];

  float* Out  = (float*)d_out;               // (4,2048,1024) f32
  float* Attn = Out + QK_ELEMS;              // (4,2048,2048) f32

  bf16* Q   = (bf16*)d_ws;                   // 16MB
  bf16* K   = Q + QK_ELEMS;                  // 16MB
  bf16* Vt  = K + QK_ELEMS;                  // 16MB
  bf16* Xb  = Vt + QK_ELEMS;                 // 16MB
  bf16* Wqb = Xb + QK_ELEMS;                 // 2MB
  bf16* Wkb = Wqb + W_ELEMS;                 // 2MB
  bf16* Wvb = Wkb + W_ELEMS;                 // 2MB  -> ws total 70MB
  bf16* Pb  = (bf16*)d_ws;                   // 32MB, aliases Q+K (dead by then)

  const int cvt_blocks = (int)((QK_ELEMS + 3 * W_ELEMS) / 4 / 256);
  cvt_kernel<<<cvt_blocks, 256, 0, stream>>>(X, Wq, Wk, Wv, Xb, Wqb, Wkb, Wvb);
  qkv_kernel<<<dim3(D / 128, (Bb * S) / 128, 3), 256, 0, stream>>>(
      Xb, Wqb, Wkb, Wvb, Q, K, Vt);
  const int ntile = (S / 128) * (S / 128 + 1) / 2;   // 136
  scores_kernel<<<dim3(ntile, Bb), 256, 0, stream>>>(Q, K, Attn);
  softmax_kernel<<<dim3(Bb * S), 256, 0, stream>>>(Attn, Pb);
  out_kernel<<<dim3(D / 128, S / 128, Bb), 256, 0, stream>>>(Pb, Vt, Out);
}

// Round 5
// 294.529 us; speedup vs baseline: 1.0896x; 1.0624x over previous
//
#include <hip/hip_runtime.h>
#include <hip/hip_bf16.h>
#include <stdint.h>
#include <math.h>

// B=4, S=2048, D=1024 causal self-attention, f32 I/O.
// out = [output (4,2048,1024) | attn_weights (4,2048,2048)] flat f32.
// Pipeline: cvt(f32->bf16) -> fused QKV GEMM (Q,K row-major; V transposed)
// -> causal-tile scores GEMM (f32 into d_out attn region) -> in-place row
// softmax (+bf16 P copy) -> P.Vt GEMM (causal K-truncation, heavy-first).
// R4->R5: XOR-swizzled LDS K-chunks (kills the 16-way bank conflict that
// BK=64's 128B row stride introduced; conflicts measured 1.9e7/dispatch).

typedef __hip_bfloat16 bf16;
typedef __attribute__((ext_vector_type(8))) short short8;
typedef __attribute__((ext_vector_type(4))) float f32x4;

#define BM 128
#define BN 128
#define BK 64

static constexpr int Bb = 4;
static constexpr int S  = 2048;
static constexpr int D  = 1024;
static constexpr size_t QK_ELEMS = (size_t)Bb * S * D;   // 8388608
static constexpr size_t SS_ELEMS = (size_t)S * S;        // 4194304 per batch
static constexpr size_t W_ELEMS  = (size_t)D * D;        // 1048576

__device__ __forceinline__ void async16(const bf16* g, bf16* l) {
  __builtin_amdgcn_global_load_lds(
      (__attribute__((address_space(1))) const void*)g,
      (__attribute__((address_space(3))) void*)l, 16, 0, 0);
}

// C[m,n] += sum_k A[m,k]*B[n,k]  (NT GEMM), 128x128 tile, BK=64, 4 waves,
// 16x16x32 bf16 MFMA. SWAP=true computes the transposed tile.
// LDS layout: row r (0..127) x 8 chunks of 16B; chunk slot s holds global
// K-chunk (s ^ (r&7)) -> bank spread is conflict-free for fragment reads.
template<bool SWAP>
__device__ __forceinline__ void gemm_core(const bf16* __restrict__ A,
                                          const bf16* __restrict__ B,
                                          int ldA, int ldB, int ksteps,
                                          bf16* As, bf16* Bs,
                                          f32x4 acc[4][4])
{
  const int tid  = threadIdx.x;
  const int lane = tid & 63;
  const int wave = tid >> 6;
  const int wm   = (wave & 1) * 64;
  const int wn   = (wave >> 1) * 64;
  const int m16  = lane & 15;
  const int kq   = lane >> 4;
  const int sw   = m16 & 7;          // row-dependent swizzle key

  // staging: 1024 x 16B chunks per tile, 4 per thread.
  // chunk c = i*256 + tid -> row r = c>>3, LDS slot = c (linear, forced by
  // global_load_lds); global column = ((c&7) ^ (r&7)) * 8  (XOR swizzle).
  int r[4], f[4];
  #pragma unroll
  for (int i = 0; i < 4; ++i) {
    const int c = tid + i * 256;
    r[i] = c >> 3;
    f[i] = (((c & 7) ^ (r[i] & 7))) * 8;
  }

  for (int ks = 0; ks < ksteps; ++ks) {
    const int k = ks * BK;
    #pragma unroll
    for (int i = 0; i < 4; ++i)
      async16(A + (size_t)r[i] * ldA + k + f[i], As + ((size_t)tid + i * 256) * 8);
    #pragma unroll
    for (int i = 0; i < 4; ++i)
      async16(B + (size_t)r[i] * ldB + k + f[i], Bs + ((size_t)tid + i * 256) * 8);
    __syncthreads();

    #pragma unroll
    for (int j = 0; j < 2; ++j) {
      const int jc = j * 4 + kq;       // logical K-chunk for this lane
      const int sl = jc ^ sw;          // swizzled LDS slot within row
      short8 af[4], bfr[4];
      #pragma unroll
      for (int i = 0; i < 4; ++i)
        af[i] = *(const short8*)&As[((wm + i * 16 + m16) * 8 + sl) * 8];
      #pragma unroll
      for (int i = 0; i < 4; ++i)
        bfr[i] = *(const short8*)&Bs[((wn + i * 16 + m16) * 8 + sl) * 8];

      #pragma unroll
      for (int mi = 0; mi < 4; ++mi) {
        #pragma unroll
        for (int ni = 0; ni < 4; ++ni) {
          if (SWAP)
            acc[mi][ni] = __builtin_amdgcn_mfma_f32_16x16x32_bf16(
                bfr[ni], af[mi], acc[mi][ni], 0, 0, 0);
          else
            acc[mi][ni] = __builtin_amdgcn_mfma_f32_16x16x32_bf16(
                af[mi], bfr[ni], acc[mi][ni], 0, 0, 0);
        }
      }
    }
    __syncthreads();
  }
}

__device__ __forceinline__ void zero_acc(f32x4 acc[4][4]) {
  #pragma unroll
  for (int mi = 0; mi < 4; ++mi)
    #pragma unroll
    for (int ni = 0; ni < 4; ++ni)
      acc[mi][ni] = (f32x4){0.f, 0.f, 0.f, 0.f};
}

// ---- Stage 0: f32 -> bf16 conversion of X, Wq, Wk, Wv --------------------
__device__ __forceinline__ unsigned short f2b(float f) {
  __hip_bfloat16 h = __float2bfloat16(f);
  return *(unsigned short*)&h;
}

__global__ __launch_bounds__(256)
void cvt_kernel(const float* __restrict__ X,  const float* __restrict__ Wq,
                const float* __restrict__ Wk, const float* __restrict__ Wv,
                bf16* __restrict__ Xb, bf16* __restrict__ Wqb,
                bf16* __restrict__ Wkb, bf16* __restrict__ Wvb)
{
  const size_t g = ((size_t)blockIdx.x * 256 + threadIdx.x) * 4;
  const float* src; bf16* dst; size_t off;
  if (g < QK_ELEMS) { src = X; dst = Xb; off = g; }
  else {
    const size_t h = g - QK_ELEMS;
    const int w = (int)(h >> 20);
    off = h & (W_ELEMS - 1);
    src = (w == 0) ? Wq : (w == 1) ? Wk : Wv;
    dst = (w == 0) ? Wqb : (w == 1) ? Wkb : Wvb;
  }
  const float4 v = *(const float4*)(src + off);
  uint2 o;
  o.x = (uint32_t)f2b(v.x) | ((uint32_t)f2b(v.y) << 16);
  o.y = (uint32_t)f2b(v.z) | ((uint32_t)f2b(v.w) << 16);
  *(uint2*)((unsigned short*)dst + off) = o;
}

// ---- Stage A: fused QKV. z=0: Q, z=1: K (row-major); z=2: Vt (transposed)
__global__ __launch_bounds__(256, 3)
void qkv_kernel(const bf16* __restrict__ X, const bf16* __restrict__ Wq,
                const bf16* __restrict__ Wk, const bf16* __restrict__ Wv,
                bf16* __restrict__ Q, bf16* __restrict__ Ko,
                bf16* __restrict__ Vt)
{
  __shared__ __align__(16) bf16 As[BM * BK];
  __shared__ __align__(16) bf16 Bs[BN * BK];
  const int nt = blockIdx.x, mt = blockIdx.y, z = blockIdx.z;
  const bf16* W = (z == 0) ? Wq : (z == 1) ? Wk : Wv;

  const int lane = threadIdx.x & 63, wave = threadIdx.x >> 6;
  const int wm = (wave & 1) * 64, wn = (wave >> 1) * 64;
  const int col0 = lane & 15, row0 = (lane >> 4) * 4;

  f32x4 acc[4][4];
  zero_acc(acc);
  if (z < 2) {
    gemm_core<false>(X + (size_t)mt * 128 * D, W + (size_t)nt * 128 * D,
                     D, D, D / BK, As, Bs, acc);
    bf16* Out = z ? Ko : Q;
    #pragma unroll
    for (int mi = 0; mi < 4; ++mi)
      #pragma unroll
      for (int ni = 0; ni < 4; ++ni)
        #pragma unroll
        for (int r = 0; r < 4; ++r) {
          const int grow = mt * 128 + wm + mi * 16 + row0 + r;
          const int gcol = nt * 128 + wn + ni * 16 + col0;
          Out[(size_t)grow * D + gcol] = __float2bfloat16(acc[mi][ni][r]);
        }
  } else {
    gemm_core<true>(X + (size_t)mt * 128 * D, W + (size_t)nt * 128 * D,
                    D, D, D / BK, As, Bs, acc);
    const int b = (mt * 128) >> 11;
    #pragma unroll
    for (int mi = 0; mi < 4; ++mi)
      #pragma unroll
      for (int ni = 0; ni < 4; ++ni)
        #pragma unroll
        for (int r = 0; r < 4; ++r) {
          const int ge = nt * 128 + wn + ni * 16 + row0 + r;      // d index
          const int gs = mt * 128 + wm + mi * 16 + col0;          // s global
          const int sl = gs & (S - 1);
          Vt[(size_t)b * D * S + (size_t)ge * S + sl] = __float2bfloat16(acc[mi][ni][r]);
        }
  }
}

// ---- Stage B: Sc = Q K^T / 32 -> f32 into d_out attn region --------------
// Flattened lower-triangle tile grid: 136 tiles/batch, zero dead blocks.
__global__ __launch_bounds__(256, 3)
void scores_kernel(const bf16* __restrict__ Q, const bf16* __restrict__ K,
                   float* __restrict__ Sc)
{
  const int t = blockIdx.x, b = blockIdx.y;
  int qt = (int)((sqrtf(8.f * (float)t + 1.f) - 1.f) * 0.5f);
  while ((qt + 1) * (qt + 2) / 2 <= t) ++qt;
  while (qt * (qt + 1) / 2 > t) --qt;
  const int kt = t - qt * (qt + 1) / 2;

  __shared__ __align__(16) bf16 As[BM * BK];
  __shared__ __align__(16) bf16 Bs[BN * BK];

  f32x4 acc[4][4];
  zero_acc(acc);
  gemm_core<false>(Q + ((size_t)b * S + qt * 128) * D,
                   K + ((size_t)b * S + kt * 128) * D,
                   D, D, D / BK, As, Bs, acc);

  const int lane = threadIdx.x & 63, wave = threadIdx.x >> 6;
  const int wm = (wave & 1) * 64, wn = (wave >> 1) * 64;
  const int col0 = lane & 15, row0 = (lane >> 4) * 4;
  float* out = Sc + (size_t)b * SS_ELEMS;
  #pragma unroll
  for (int mi = 0; mi < 4; ++mi)
    #pragma unroll
    for (int ni = 0; ni < 4; ++ni)
      #pragma unroll
      for (int r = 0; r < 4; ++r) {
        const int gq = qt * 128 + wm + mi * 16 + row0 + r;
        const int gk = kt * 128 + wn + ni * 16 + col0;
        out[(size_t)gq * S + gk] = acc[mi][ni][r] * 0.03125f;
      }
}

// ---- Stage C: causal row softmax in place (f32) + bf16 P copy ------------
__device__ __forceinline__ float wave_max(float v) {
  #pragma unroll
  for (int o = 32; o > 0; o >>= 1) v = fmaxf(v, __shfl_xor(v, o, 64));
  return v;
}
__device__ __forceinline__ float wave_sum(float v) {
  #pragma unroll
  for (int o = 32; o > 0; o >>= 1) v += __shfl_xor(v, o, 64);
  return v;
}

__global__ __launch_bounds__(256)
void softmax_kernel(float* __restrict__ Attn, bf16* __restrict__ Pb)
{
  const int row = blockIdx.x;            // 0..8191
  const int b = row >> 11, i = row & (S - 1);
  float* s = Attn + (size_t)b * SS_ELEMS + (size_t)i * S;
  bf16* p  = Pb   + (size_t)b * SS_ELEMS + (size_t)i * S;
  const int t = threadIdx.x;
  const int lane = t & 63, wave = t >> 6;
  __shared__ float red[4];

  float vals[8];
  #pragma unroll
  for (int u = 0; u < 8; ++u) {
    const int j = t + u * 256;
    vals[u] = (j <= i) ? s[j] : -INFINITY;
  }
  float m = -INFINITY;
  #pragma unroll
  for (int u = 0; u < 8; ++u) m = fmaxf(m, vals[u]);
  m = wave_max(m);
  if (lane == 0) red[wave] = m;
  __syncthreads();
  m = fmaxf(fmaxf(red[0], red[1]), fmaxf(red[2], red[3]));
  __syncthreads();

  float sum = 0.f;
  #pragma unroll
  for (int u = 0; u < 8; ++u) {
    const float e = expf(vals[u] - m);   // expf(-inf)=0 handles masked
    vals[u] = e;
    sum += e;
  }
  sum = wave_sum(sum);
  if (lane == 0) red[wave] = sum;
  __syncthreads();
  sum = red[0] + red[1] + red[2] + red[3];
  const float inv = 1.f / sum;           // sum >= 1 (diag term is exp(0))

  #pragma unroll
  for (int u = 0; u < 8; ++u) {
    const int j = t + u * 256;
    const float w = vals[u] * inv;
    s[j] = w;                            // f32 attn weights (exact output)
    p[j] = __float2bfloat16(w);          // bf16 copy for the PV GEMM
  }
}

// ---- Stage D: O = P Vt^T (causal K-truncation), heavy qt first -----------
__global__ __launch_bounds__(256, 3)
void out_kernel(const bf16* __restrict__ P, const bf16* __restrict__ Vt,
                float* __restrict__ O)
{
  const int dt = blockIdx.x, qt = (S / 128 - 1) - blockIdx.y, b = blockIdx.z;
  __shared__ __align__(16) bf16 As[BM * BK];
  __shared__ __align__(16) bf16 Bs[BN * BK];

  f32x4 acc[4][4];
  zero_acc(acc);
  const int ksteps = (qt + 1) * (128 / BK);   // only k <= q-block end nonzero
  gemm_core<false>(P + (size_t)b * SS_ELEMS + (size_t)qt * 128 * S,
                   Vt + (size_t)b * D * S + (size_t)dt * 128 * S,
                   S, S, ksteps, As, Bs, acc);

  const int lane = threadIdx.x & 63, wave = threadIdx.x >> 6;
  const int wm = (wave & 1) * 64, wn = (wave >> 1) * 64;
  const int col0 = lane & 15, row0 = (lane >> 4) * 4;
  #pragma unroll
  for (int mi = 0; mi < 4; ++mi)
    #pragma unroll
    for (int ni = 0; ni < 4; ++ni)
      #pragma unroll
      for (int r = 0; r < 4; ++r) {
        const int gq = qt * 128 + wm + mi * 16 + row0 + r;
        const int gd = dt * 128 + wn + ni * 16 + col0;
        O[((size_t)b * S + gq) * D + gd] = acc[mi][ni][r];
      }
}

extern "C" void kernel_launch(void* const* d_in, const int* in_sizes, int n_in,
                              void* d_out, int out_size, void* d_ws, size_t ws_size,
                              hipStream_t stream) {
  const float* X  = (const float*)d_in[0];
  // d_in[1] = causal mask (int32 tril) — applied analytically, not read.
  const float* Wq = (const float*)d_in[2];
  const float* Wk = (const float*)d_in[3];
  const float* Wv = (const float*)d_in[4];

  float* Out  = (float*)d_out;               // (4,2048,1024) f32
  float* Attn = Out + QK_ELEMS;              // (4,2048,2048) f32

  bf16* Q   = (bf16*)d_ws;                   // 16MB
  bf16* K   = Q + QK_ELEMS;                  // 16MB
  bf16* Vt  = K + QK_ELEMS;                  // 16MB
  bf16* Xb  = Vt + QK_ELEMS;                 // 16MB
  bf16* Wqb = Xb + QK_ELEMS;                 // 2MB
  bf16* Wkb = Wqb + W_ELEMS;                 // 2MB
  bf16* Wvb = Wkb + W_ELEMS;                 // 2MB  -> ws total 70MB
  bf16* Pb  = (bf16*)d_ws;                   // 32MB, aliases Q+K (dead by then)

  const int cvt_blocks = (int)((QK_ELEMS + 3 * W_ELEMS) / 4 / 256);
  cvt_kernel<<<cvt_blocks, 256, 0, stream>>>(X, Wq, Wk, Wv, Xb, Wqb, Wkb, Wvb);
  qkv_kernel<<<dim3(D / 128, (Bb * S) / 128, 3), 256, 0, stream>>>(
      Xb, Wqb, Wkb, Wvb, Q, K, Vt);
  const int ntile = (S / 128) * (S / 128 + 1) / 2;   // 136
  scores_kernel<<<dim3(ntile, Bb), 256, 0, stream>>>(Q, K, Attn);
  softmax_kernel<<<dim3(Bb * S), 256, 0, stream>>>(Attn, Pb);
  out_kernel<<<dim3(D / 128, S / 128, Bb), 256, 0, stream>>>(Pb, Vt, Out);
}

// Round 6
// 276.307 us; speedup vs baseline: 1.1615x; 1.0659x over previous
//
#include <hip/hip_runtime.h>
#include <hip/hip_bf16.h>
#include <stdint.h>
#include <math.h>

// B=4, S=2048, D=1024 causal self-attention, f32 I/O.
// out = [output (4,2048,1024) | attn_weights (4,2048,2048)] flat f32.
// Pipeline: cvt(f32->bf16) -> fused QKV GEMM (Q,K row-major; V transposed)
// -> causal-tile scores GEMM (f32 into d_out attn region) -> in-place row
// softmax (+bf16 P copy) -> P.Vt GEMM (causal K-truncation, heavy-first).
// R5->R6: XCD-aware block swizzles for qkv and out (colocate blocks sharing
// A-tiles on one XCD's L2; FETCH_SIZE was 178MB vs ~22MB ideal on qkv).

typedef __hip_bfloat16 bf16;
typedef __attribute__((ext_vector_type(8))) short short8;
typedef __attribute__((ext_vector_type(4))) float f32x4;

#define BM 128
#define BN 128
#define BK 64

static constexpr int Bb = 4;
static constexpr int S  = 2048;
static constexpr int D  = 1024;
static constexpr size_t QK_ELEMS = (size_t)Bb * S * D;   // 8388608
static constexpr size_t SS_ELEMS = (size_t)S * S;        // 4194304 per batch
static constexpr size_t W_ELEMS  = (size_t)D * D;        // 1048576

__device__ __forceinline__ void async16(const bf16* g, bf16* l) {
  __builtin_amdgcn_global_load_lds(
      (__attribute__((address_space(1))) const void*)g,
      (__attribute__((address_space(3))) void*)l, 16, 0, 0);
}

// C[m,n] += sum_k A[m,k]*B[n,k]  (NT GEMM), 128x128 tile, BK=64, 4 waves,
// 16x16x32 bf16 MFMA. SWAP=true computes the transposed tile.
// LDS layout: row r (0..127) x 8 chunks of 16B; chunk slot s holds global
// K-chunk (s ^ (r&7)) -> bank spread is conflict-free for fragment reads.
template<bool SWAP>
__device__ __forceinline__ void gemm_core(const bf16* __restrict__ A,
                                          const bf16* __restrict__ B,
                                          int ldA, int ldB, int ksteps,
                                          bf16* As, bf16* Bs,
                                          f32x4 acc[4][4])
{
  const int tid  = threadIdx.x;
  const int lane = tid & 63;
  const int wave = tid >> 6;
  const int wm   = (wave & 1) * 64;
  const int wn   = (wave >> 1) * 64;
  const int m16  = lane & 15;
  const int kq   = lane >> 4;
  const int sw   = m16 & 7;          // row-dependent swizzle key

  // staging: 1024 x 16B chunks per tile, 4 per thread.
  // chunk c = i*256 + tid -> row r = c>>3, LDS slot = c (linear, forced by
  // global_load_lds); global column = ((c&7) ^ (r&7)) * 8  (XOR swizzle).
  int r[4], f[4];
  #pragma unroll
  for (int i = 0; i < 4; ++i) {
    const int c = tid + i * 256;
    r[i] = c >> 3;
    f[i] = (((c & 7) ^ (r[i] & 7))) * 8;
  }

  for (int ks = 0; ks < ksteps; ++ks) {
    const int k = ks * BK;
    #pragma unroll
    for (int i = 0; i < 4; ++i)
      async16(A + (size_t)r[i] * ldA + k + f[i], As + ((size_t)tid + i * 256) * 8);
    #pragma unroll
    for (int i = 0; i < 4; ++i)
      async16(B + (size_t)r[i] * ldB + k + f[i], Bs + ((size_t)tid + i * 256) * 8);
    __syncthreads();

    #pragma unroll
    for (int j = 0; j < 2; ++j) {
      const int jc = j * 4 + kq;       // logical K-chunk for this lane
      const int sl = jc ^ sw;          // swizzled LDS slot within row
      short8 af[4], bfr[4];
      #pragma unroll
      for (int i = 0; i < 4; ++i)
        af[i] = *(const short8*)&As[((wm + i * 16 + m16) * 8 + sl) * 8];
      #pragma unroll
      for (int i = 0; i < 4; ++i)
        bfr[i] = *(const short8*)&Bs[((wn + i * 16 + m16) * 8 + sl) * 8];

      #pragma unroll
      for (int mi = 0; mi < 4; ++mi) {
        #pragma unroll
        for (int ni = 0; ni < 4; ++ni) {
          if (SWAP)
            acc[mi][ni] = __builtin_amdgcn_mfma_f32_16x16x32_bf16(
                bfr[ni], af[mi], acc[mi][ni], 0, 0, 0);
          else
            acc[mi][ni] = __builtin_amdgcn_mfma_f32_16x16x32_bf16(
                af[mi], bfr[ni], acc[mi][ni], 0, 0, 0);
        }
      }
    }
    __syncthreads();
  }
}

__device__ __forceinline__ void zero_acc(f32x4 acc[4][4]) {
  #pragma unroll
  for (int mi = 0; mi < 4; ++mi)
    #pragma unroll
    for (int ni = 0; ni < 4; ++ni)
      acc[mi][ni] = (f32x4){0.f, 0.f, 0.f, 0.f};
}

// ---- Stage 0: f32 -> bf16 conversion of X, Wq, Wk, Wv --------------------
__device__ __forceinline__ unsigned short f2b(float f) {
  __hip_bfloat16 h = __float2bfloat16(f);
  return *(unsigned short*)&h;
}

__global__ __launch_bounds__(256)
void cvt_kernel(const float* __restrict__ X,  const float* __restrict__ Wq,
                const float* __restrict__ Wk, const float* __restrict__ Wv,
                bf16* __restrict__ Xb, bf16* __restrict__ Wqb,
                bf16* __restrict__ Wkb, bf16* __restrict__ Wvb)
{
  const size_t g = ((size_t)blockIdx.x * 256 + threadIdx.x) * 4;
  const float* src; bf16* dst; size_t off;
  if (g < QK_ELEMS) { src = X; dst = Xb; off = g; }
  else {
    const size_t h = g - QK_ELEMS;
    const int w = (int)(h >> 20);
    off = h & (W_ELEMS - 1);
    src = (w == 0) ? Wq : (w == 1) ? Wk : Wv;
    dst = (w == 0) ? Wqb : (w == 1) ? Wkb : Wvb;
  }
  const float4 v = *(const float4*)(src + off);
  uint2 o;
  o.x = (uint32_t)f2b(v.x) | ((uint32_t)f2b(v.y) << 16);
  o.y = (uint32_t)f2b(v.z) | ((uint32_t)f2b(v.w) << 16);
  *(uint2*)((unsigned short*)dst + off) = o;
}

// ---- Stage A: fused QKV. z=0: Q, z=1: K (row-major); z=2: Vt (transposed)
// Linear grid of 1536 with XCD-aware decode: blocks with the same (z,mt)
// (sharing the X row-tile) land on one XCD; all z for one mt share the XCD
// too (64 = 0 mod 8), so each X row-tile is fetched from HBM once.
__global__ __launch_bounds__(256, 3)
void qkv_kernel(const bf16* __restrict__ X, const bf16* __restrict__ Wq,
                const bf16* __restrict__ Wk, const bf16* __restrict__ Wv,
                bf16* __restrict__ Q, bf16* __restrict__ Ko,
                bf16* __restrict__ Vt)
{
  __shared__ __align__(16) bf16 As[BM * BK];
  __shared__ __align__(16) bf16 Bs[BN * BK];
  const int L = blockIdx.x;               // 0..1535
  const int x = L & 7;                    // XCD (dispatch round-robin %8)
  const int s = L >> 3;                   // 0..191
  const int nt  = s & 7;
  const int zmt = ((s >> 3) << 3) | x;    // 0..191, fixed XCD per (z,mt)
  const int z   = zmt >> 6;
  const int mt  = zmt & 63;
  const bf16* W = (z == 0) ? Wq : (z == 1) ? Wk : Wv;

  const int lane = threadIdx.x & 63, wave = threadIdx.x >> 6;
  const int wm = (wave & 1) * 64, wn = (wave >> 1) * 64;
  const int col0 = lane & 15, row0 = (lane >> 4) * 4;

  f32x4 acc[4][4];
  zero_acc(acc);
  if (z < 2) {
    gemm_core<false>(X + (size_t)mt * 128 * D, W + (size_t)nt * 128 * D,
                     D, D, D / BK, As, Bs, acc);
    bf16* Out = z ? Ko : Q;
    #pragma unroll
    for (int mi = 0; mi < 4; ++mi)
      #pragma unroll
      for (int ni = 0; ni < 4; ++ni)
        #pragma unroll
        for (int r = 0; r < 4; ++r) {
          const int grow = mt * 128 + wm + mi * 16 + row0 + r;
          const int gcol = nt * 128 + wn + ni * 16 + col0;
          Out[(size_t)grow * D + gcol] = __float2bfloat16(acc[mi][ni][r]);
        }
  } else {
    gemm_core<true>(X + (size_t)mt * 128 * D, W + (size_t)nt * 128 * D,
                    D, D, D / BK, As, Bs, acc);
    const int b = (mt * 128) >> 11;
    #pragma unroll
    for (int mi = 0; mi < 4; ++mi)
      #pragma unroll
      for (int ni = 0; ni < 4; ++ni)
        #pragma unroll
        for (int r = 0; r < 4; ++r) {
          const int ge = nt * 128 + wn + ni * 16 + row0 + r;      // d index
          const int gs = mt * 128 + wm + mi * 16 + col0;          // s global
          const int sl = gs & (S - 1);
          Vt[(size_t)b * D * S + (size_t)ge * S + sl] = __float2bfloat16(acc[mi][ni][r]);
        }
  }
}

// ---- Stage B: Sc = Q K^T / 32 -> f32 into d_out attn region --------------
// Flattened lower-triangle tile grid: 136 tiles/batch, zero dead blocks.
__global__ __launch_bounds__(256, 3)
void scores_kernel(const bf16* __restrict__ Q, const bf16* __restrict__ K,
                   float* __restrict__ Sc)
{
  const int t = blockIdx.x, b = blockIdx.y;
  int qt = (int)((sqrtf(8.f * (float)t + 1.f) - 1.f) * 0.5f);
  while ((qt + 1) * (qt + 2) / 2 <= t) ++qt;
  while (qt * (qt + 1) / 2 > t) --qt;
  const int kt = t - qt * (qt + 1) / 2;

  __shared__ __align__(16) bf16 As[BM * BK];
  __shared__ __align__(16) bf16 Bs[BN * BK];

  f32x4 acc[4][4];
  zero_acc(acc);
  gemm_core<false>(Q + ((size_t)b * S + qt * 128) * D,
                   K + ((size_t)b * S + kt * 128) * D,
                   D, D, D / BK, As, Bs, acc);

  const int lane = threadIdx.x & 63, wave = threadIdx.x >> 6;
  const int wm = (wave & 1) * 64, wn = (wave >> 1) * 64;
  const int col0 = lane & 15, row0 = (lane >> 4) * 4;
  float* out = Sc + (size_t)b * SS_ELEMS;
  #pragma unroll
  for (int mi = 0; mi < 4; ++mi)
    #pragma unroll
    for (int ni = 0; ni < 4; ++ni)
      #pragma unroll
      for (int r = 0; r < 4; ++r) {
        const int gq = qt * 128 + wm + mi * 16 + row0 + r;
        const int gk = kt * 128 + wn + ni * 16 + col0;
        out[(size_t)gq * S + gk] = acc[mi][ni][r] * 0.03125f;
      }
}

// ---- Stage C: causal row softmax in place (f32) + bf16 P copy ------------
__device__ __forceinline__ float wave_max(float v) {
  #pragma unroll
  for (int o = 32; o > 0; o >>= 1) v = fmaxf(v, __shfl_xor(v, o, 64));
  return v;
}
__device__ __forceinline__ float wave_sum(float v) {
  #pragma unroll
  for (int o = 32; o > 0; o >>= 1) v += __shfl_xor(v, o, 64);
  return v;
}

__global__ __launch_bounds__(256)
void softmax_kernel(float* __restrict__ Attn, bf16* __restrict__ Pb)
{
  const int row = blockIdx.x;            // 0..8191
  const int b = row >> 11, i = row & (S - 1);
  float* s = Attn + (size_t)b * SS_ELEMS + (size_t)i * S;
  bf16* p  = Pb   + (size_t)b * SS_ELEMS + (size_t)i * S;
  const int t = threadIdx.x;
  const int lane = t & 63, wave = t >> 6;
  __shared__ float red[4];

  float vals[8];
  #pragma unroll
  for (int u = 0; u < 8; ++u) {
    const int j = t + u * 256;
    vals[u] = (j <= i) ? s[j] : -INFINITY;
  }
  float m = -INFINITY;
  #pragma unroll
  for (int u = 0; u < 8; ++u) m = fmaxf(m, vals[u]);
  m = wave_max(m);
  if (lane == 0) red[wave] = m;
  __syncthreads();
  m = fmaxf(fmaxf(red[0], red[1]), fmaxf(red[2], red[3]));
  __syncthreads();

  float sum = 0.f;
  #pragma unroll
  for (int u = 0; u < 8; ++u) {
    const float e = expf(vals[u] - m);   // expf(-inf)=0 handles masked
    vals[u] = e;
    sum += e;
  }
  sum = wave_sum(sum);
  if (lane == 0) red[wave] = sum;
  __syncthreads();
  sum = red[0] + red[1] + red[2] + red[3];
  const float inv = 1.f / sum;           // sum >= 1 (diag term is exp(0))

  #pragma unroll
  for (int u = 0; u < 8; ++u) {
    const int j = t + u * 256;
    const float w = vals[u] * inv;
    s[j] = w;                            // f32 attn weights (exact output)
    p[j] = __float2bfloat16(w);          // bf16 copy for the PV GEMM
  }
}

// ---- Stage D: O = P Vt^T (causal K-truncation) ---------------------------
// Linear grid of 512, XCD-aware: all 8 dt-blocks of one (b,qt) (sharing the
// P row-strip) on one XCD; heavy-qt groups dispatched first.
__global__ __launch_bounds__(256, 3)
void out_kernel(const bf16* __restrict__ P, const bf16* __restrict__ Vt,
                float* __restrict__ O)
{
  const int L = blockIdx.x;               // 0..511
  const int x = L & 7;                    // XCD
  const int s = L >> 3;                   // 0..63
  const int dt  = s & 7;
  const int qtb = ((s >> 3) << 3) | x;    // 0..63, fixed XCD per (b,qt)
  const int qt  = 15 - (qtb >> 2);        // heavy-first (large qt at low L)
  const int b   = qtb & 3;

  __shared__ __align__(16) bf16 As[BM * BK];
  __shared__ __align__(16) bf16 Bs[BN * BK];

  f32x4 acc[4][4];
  zero_acc(acc);
  const int ksteps = (qt + 1) * (128 / BK);   // only k <= q-block end nonzero
  gemm_core<false>(P + (size_t)b * SS_ELEMS + (size_t)qt * 128 * S,
                   Vt + (size_t)b * D * S + (size_t)dt * 128 * S,
                   S, S, ksteps, As, Bs, acc);

  const int lane = threadIdx.x & 63, wave = threadIdx.x >> 6;
  const int wm = (wave & 1) * 64, wn = (wave >> 1) * 64;
  const int col0 = lane & 15, row0 = (lane >> 4) * 4;
  #pragma unroll
  for (int mi = 0; mi < 4; ++mi)
    #pragma unroll
    for (int ni = 0; ni < 4; ++ni)
      #pragma unroll
      for (int r = 0; r < 4; ++r) {
        const int gq = qt * 128 + wm + mi * 16 + row0 + r;
        const int gd = dt * 128 + wn + ni * 16 + col0;
        O[((size_t)b * S + gq) * D + gd] = acc[mi][ni][r];
      }
}

extern "C" void kernel_launch(void* const* d_in, const int* in_sizes, int n_in,
                              void* d_out, int out_size, void* d_ws, size_t ws_size,
                              hipStream_t stream) {
  const float* X  = (const float*)d_in[0];
  // d_in[1] = causal mask (int32 tril) — applied analytically, not read.
  const float* Wq = (const float*)d_in[2];
  const float* Wk = (const float*)d_in[3];
  const float* Wv = (const float*)d_in[4];

  float* Out  = (float*)d_out;               // (4,2048,1024) f32
  float* Attn = Out + QK_ELEMS;              // (4,2048,2048) f32

  bf16* Q   = (bf16*)d_ws;                   // 16MB
  bf16* K   = Q + QK_ELEMS;                  // 16MB
  bf16* Vt  = K + QK_ELEMS;                  // 16MB
  bf16* Xb  = Vt + QK_ELEMS;                 // 16MB
  bf16* Wqb = Xb + QK_ELEMS;                 // 2MB
  bf16* Wkb = Wqb + W_ELEMS;                 // 2MB
  bf16* Wvb = Wkb + W_ELEMS;                 // 2MB  -> ws total 70MB
  bf16* Pb  = (bf16*)d_ws;                   // 32MB, aliases Q+K (dead by then)

  const int cvt_blocks = (int)((QK_ELEMS + 3 * W_ELEMS) / 4 / 256);
  cvt_kernel<<<cvt_blocks, 256, 0, stream>>>(X, Wq, Wk, Wv, Xb, Wqb, Wkb, Wvb);
  qkv_kernel<<<dim3(1536), 256, 0, stream>>>(Xb, Wqb, Wkb, Wvb, Q, K, Vt);
  const int ntile = (S / 128) * (S / 128 + 1) / 2;   // 136
  scores_kernel<<<dim3(ntile, Bb), 256, 0, stream>>>(Q, K, Attn);
  softmax_kernel<<<dim3(Bb * S), 256, 0, stream>>>(Attn, Pb);
  out_kernel<<<dim3(512), 256, 0, stream>>>(Pb, Vt, Out);
}

// Round 7
// 275.484 us; speedup vs baseline: 1.1650x; 1.0030x over previous
//
#include <hip/hip_runtime.h>
#include <hip/hip_bf16.h>
#include <stdint.h>
#include <math.h>

// B=4, S=2048, D=1024 causal self-attention, f32 I/O.
// out = [output (4,2048,1024) | attn_weights (4,2048,2048)] flat f32.
// Pipeline: cvt(f32->bf16) -> fused QKV GEMM (Q,K row-major; V transposed)
// -> causal-tile scores GEMM (f32 into d_out attn region) -> in-place row
// softmax (+bf16 P copy) -> P.Vt GEMM (causal K-truncation, heavy-first).
// R6->R7: __launch_bounds__(256,4) on GEMMs (4 blocks/CU; VGPR 64 and
// 32KB LDS both fit), float4-vectorized softmax with causal read-skip and
// diagonal-truncated bf16 P writes.

typedef __hip_bfloat16 bf16;
typedef __attribute__((ext_vector_type(8))) short short8;
typedef __attribute__((ext_vector_type(4))) float f32x4;

#define BM 128
#define BN 128
#define BK 64

static constexpr int Bb = 4;
static constexpr int S  = 2048;
static constexpr int D  = 1024;
static constexpr size_t QK_ELEMS = (size_t)Bb * S * D;   // 8388608
static constexpr size_t SS_ELEMS = (size_t)S * S;        // 4194304 per batch
static constexpr size_t W_ELEMS  = (size_t)D * D;        // 1048576

__device__ __forceinline__ void async16(const bf16* g, bf16* l) {
  __builtin_amdgcn_global_load_lds(
      (__attribute__((address_space(1))) const void*)g,
      (__attribute__((address_space(3))) void*)l, 16, 0, 0);
}

// C[m,n] += sum_k A[m,k]*B[n,k]  (NT GEMM), 128x128 tile, BK=64, 4 waves,
// 16x16x32 bf16 MFMA. SWAP=true computes the transposed tile.
// LDS: row r x 8 chunks of 16B; slot s holds global K-chunk (s ^ (r&7)) ->
// conflict-free fragment reads (verified: SQ_LDS_BANK_CONFLICT 1.9e7 -> 0).
template<bool SWAP>
__device__ __forceinline__ void gemm_core(const bf16* __restrict__ A,
                                          const bf16* __restrict__ B,
                                          int ldA, int ldB, int ksteps,
                                          bf16* As, bf16* Bs,
                                          f32x4 acc[4][4])
{
  const int tid  = threadIdx.x;
  const int lane = tid & 63;
  const int wave = tid >> 6;
  const int wm   = (wave & 1) * 64;
  const int wn   = (wave >> 1) * 64;
  const int m16  = lane & 15;
  const int kq   = lane >> 4;
  const int sw   = m16 & 7;          // row-dependent swizzle key

  int r[4], f[4];
  #pragma unroll
  for (int i = 0; i < 4; ++i) {
    const int c = tid + i * 256;
    r[i] = c >> 3;
    f[i] = (((c & 7) ^ (r[i] & 7))) * 8;
  }

  for (int ks = 0; ks < ksteps; ++ks) {
    const int k = ks * BK;
    #pragma unroll
    for (int i = 0; i < 4; ++i)
      async16(A + (size_t)r[i] * ldA + k + f[i], As + ((size_t)tid + i * 256) * 8);
    #pragma unroll
    for (int i = 0; i < 4; ++i)
      async16(B + (size_t)r[i] * ldB + k + f[i], Bs + ((size_t)tid + i * 256) * 8);
    __syncthreads();

    #pragma unroll
    for (int j = 0; j < 2; ++j) {
      const int jc = j * 4 + kq;       // logical K-chunk for this lane
      const int sl = jc ^ sw;          // swizzled LDS slot within row
      short8 af[4], bfr[4];
      #pragma unroll
      for (int i = 0; i < 4; ++i)
        af[i] = *(const short8*)&As[((wm + i * 16 + m16) * 8 + sl) * 8];
      #pragma unroll
      for (int i = 0; i < 4; ++i)
        bfr[i] = *(const short8*)&Bs[((wn + i * 16 + m16) * 8 + sl) * 8];

      #pragma unroll
      for (int mi = 0; mi < 4; ++mi) {
        #pragma unroll
        for (int ni = 0; ni < 4; ++ni) {
          if (SWAP)
            acc[mi][ni] = __builtin_amdgcn_mfma_f32_16x16x32_bf16(
                bfr[ni], af[mi], acc[mi][ni], 0, 0, 0);
          else
            acc[mi][ni] = __builtin_amdgcn_mfma_f32_16x16x32_bf16(
                af[mi], bfr[ni], acc[mi][ni], 0, 0, 0);
        }
      }
    }
    __syncthreads();
  }
}

__device__ __forceinline__ void zero_acc(f32x4 acc[4][4]) {
  #pragma unroll
  for (int mi = 0; mi < 4; ++mi)
    #pragma unroll
    for (int ni = 0; ni < 4; ++ni)
      acc[mi][ni] = (f32x4){0.f, 0.f, 0.f, 0.f};
}

// ---- Stage 0: f32 -> bf16 conversion of X, Wq, Wk, Wv --------------------
__device__ __forceinline__ unsigned short f2b(float f) {
  __hip_bfloat16 h = __float2bfloat16(f);
  return *(unsigned short*)&h;
}

__global__ __launch_bounds__(256)
void cvt_kernel(const float* __restrict__ X,  const float* __restrict__ Wq,
                const float* __restrict__ Wk, const float* __restrict__ Wv,
                bf16* __restrict__ Xb, bf16* __restrict__ Wqb,
                bf16* __restrict__ Wkb, bf16* __restrict__ Wvb)
{
  const size_t g = ((size_t)blockIdx.x * 256 + threadIdx.x) * 4;
  const float* src; bf16* dst; size_t off;
  if (g < QK_ELEMS) { src = X; dst = Xb; off = g; }
  else {
    const size_t h = g - QK_ELEMS;
    const int w = (int)(h >> 20);
    off = h & (W_ELEMS - 1);
    src = (w == 0) ? Wq : (w == 1) ? Wk : Wv;
    dst = (w == 0) ? Wqb : (w == 1) ? Wkb : Wvb;
  }
  const float4 v = *(const float4*)(src + off);
  uint2 o;
  o.x = (uint32_t)f2b(v.x) | ((uint32_t)f2b(v.y) << 16);
  o.y = (uint32_t)f2b(v.z) | ((uint32_t)f2b(v.w) << 16);
  *(uint2*)((unsigned short*)dst + off) = o;
}

// ---- Stage A: fused QKV. z=0: Q, z=1: K (row-major); z=2: Vt (transposed)
// Linear grid 1536, XCD-aware decode: all nt (and all z) for one mt share
// one XCD -> each X row-tile fetched from HBM once (FETCH 178->44MB).
__global__ __launch_bounds__(256, 4)
void qkv_kernel(const bf16* __restrict__ X, const bf16* __restrict__ Wq,
                const bf16* __restrict__ Wk, const bf16* __restrict__ Wv,
                bf16* __restrict__ Q, bf16* __restrict__ Ko,
                bf16* __restrict__ Vt)
{
  __shared__ __align__(16) bf16 As[BM * BK];
  __shared__ __align__(16) bf16 Bs[BN * BK];
  const int L = blockIdx.x;               // 0..1535
  const int x = L & 7;                    // XCD (dispatch round-robin %8)
  const int s = L >> 3;                   // 0..191
  const int nt  = s & 7;
  const int zmt = ((s >> 3) << 3) | x;    // 0..191, fixed XCD per (z,mt)
  const int z   = zmt >> 6;
  const int mt  = zmt & 63;
  const bf16* W = (z == 0) ? Wq : (z == 1) ? Wk : Wv;

  const int lane = threadIdx.x & 63, wave = threadIdx.x >> 6;
  const int wm = (wave & 1) * 64, wn = (wave >> 1) * 64;
  const int col0 = lane & 15, row0 = (lane >> 4) * 4;

  f32x4 acc[4][4];
  zero_acc(acc);
  if (z < 2) {
    gemm_core<false>(X + (size_t)mt * 128 * D, W + (size_t)nt * 128 * D,
                     D, D, D / BK, As, Bs, acc);
    bf16* Out = z ? Ko : Q;
    #pragma unroll
    for (int mi = 0; mi < 4; ++mi)
      #pragma unroll
      for (int ni = 0; ni < 4; ++ni)
        #pragma unroll
        for (int r = 0; r < 4; ++r) {
          const int grow = mt * 128 + wm + mi * 16 + row0 + r;
          const int gcol = nt * 128 + wn + ni * 16 + col0;
          Out[(size_t)grow * D + gcol] = __float2bfloat16(acc[mi][ni][r]);
        }
  } else {
    gemm_core<true>(X + (size_t)mt * 128 * D, W + (size_t)nt * 128 * D,
                    D, D, D / BK, As, Bs, acc);
    const int b = (mt * 128) >> 11;
    #pragma unroll
    for (int mi = 0; mi < 4; ++mi)
      #pragma unroll
      for (int ni = 0; ni < 4; ++ni)
        #pragma unroll
        for (int r = 0; r < 4; ++r) {
          const int ge = nt * 128 + wn + ni * 16 + row0 + r;      // d index
          const int gs = mt * 128 + wm + mi * 16 + col0;          // s global
          const int sl = gs & (S - 1);
          Vt[(size_t)b * D * S + (size_t)ge * S + sl] = __float2bfloat16(acc[mi][ni][r]);
        }
  }
}

// ---- Stage B: Sc = Q K^T / 32 -> f32 into d_out attn region --------------
// Flattened lower-triangle tile grid: 136 tiles/batch, zero dead blocks.
__global__ __launch_bounds__(256, 4)
void scores_kernel(const bf16* __restrict__ Q, const bf16* __restrict__ K,
                   float* __restrict__ Sc)
{
  const int t = blockIdx.x, b = blockIdx.y;
  int qt = (int)((sqrtf(8.f * (float)t + 1.f) - 1.f) * 0.5f);
  while ((qt + 1) * (qt + 2) / 2 <= t) ++qt;
  while (qt * (qt + 1) / 2 > t) --qt;
  const int kt = t - qt * (qt + 1) / 2;

  __shared__ __align__(16) bf16 As[BM * BK];
  __shared__ __align__(16) bf16 Bs[BN * BK];

  f32x4 acc[4][4];
  zero_acc(acc);
  gemm_core<false>(Q + ((size_t)b * S + qt * 128) * D,
                   K + ((size_t)b * S + kt * 128) * D,
                   D, D, D / BK, As, Bs, acc);

  const int lane = threadIdx.x & 63, wave = threadIdx.x >> 6;
  const int wm = (wave & 1) * 64, wn = (wave >> 1) * 64;
  const int col0 = lane & 15, row0 = (lane >> 4) * 4;
  float* out = Sc + (size_t)b * SS_ELEMS;
  #pragma unroll
  for (int mi = 0; mi < 4; ++mi)
    #pragma unroll
    for (int ni = 0; ni < 4; ++ni)
      #pragma unroll
      for (int r = 0; r < 4; ++r) {
        const int gq = qt * 128 + wm + mi * 16 + row0 + r;
        const int gk = kt * 128 + wn + ni * 16 + col0;
        out[(size_t)gq * S + gk] = acc[mi][ni][r] * 0.03125f;
      }
}

// ---- Stage C: causal row softmax in place (f32) + bf16 P copy ------------
// float4 vectorized; skips loads above the diagonal; bf16 P written only up
// to the diagonal-tile end (out_kernel never reads past it).
__device__ __forceinline__ float wave_max(float v) {
  #pragma unroll
  for (int o = 32; o > 0; o >>= 1) v = fmaxf(v, __shfl_xor(v, o, 64));
  return v;
}
__device__ __forceinline__ float wave_sum(float v) {
  #pragma unroll
  for (int o = 32; o > 0; o >>= 1) v += __shfl_xor(v, o, 64);
  return v;
}

__global__ __launch_bounds__(256)
void softmax_kernel(float* __restrict__ Attn, bf16* __restrict__ Pb)
{
  const int row = blockIdx.x;            // 0..8191
  const int b = row >> 11, i = row & (S - 1);
  float* s = Attn + (size_t)b * SS_ELEMS + (size_t)i * S;
  bf16* p  = Pb   + (size_t)b * SS_ELEMS + (size_t)i * S;
  const int t = threadIdx.x;
  const int lane = t & 63, wave = t >> 6;
  __shared__ float red[4];

  float4 v[2];
  #pragma unroll
  for (int u = 0; u < 2; ++u) {
    const int base = (t + u * 256) * 4;
    if (base + 3 <= i) {
      v[u] = *(const float4*)(s + base);
    } else if (base > i) {
      v[u] = make_float4(-INFINITY, -INFINITY, -INFINITY, -INFINITY);
    } else {
      v[u].x = (base + 0 <= i) ? s[base + 0] : -INFINITY;
      v[u].y = (base + 1 <= i) ? s[base + 1] : -INFINITY;
      v[u].z = (base + 2 <= i) ? s[base + 2] : -INFINITY;
      v[u].w = (base + 3 <= i) ? s[base + 3] : -INFINITY;
    }
  }

  float m = -INFINITY;
  #pragma unroll
  for (int u = 0; u < 2; ++u)
    m = fmaxf(m, fmaxf(fmaxf(v[u].x, v[u].y), fmaxf(v[u].z, v[u].w)));
  m = wave_max(m);
  if (lane == 0) red[wave] = m;
  __syncthreads();
  m = fmaxf(fmaxf(red[0], red[1]), fmaxf(red[2], red[3]));
  __syncthreads();

  float sum = 0.f;
  #pragma unroll
  for (int u = 0; u < 2; ++u) {
    v[u].x = expf(v[u].x - m); sum += v[u].x;
    v[u].y = expf(v[u].y - m); sum += v[u].y;
    v[u].z = expf(v[u].z - m); sum += v[u].z;
    v[u].w = expf(v[u].w - m); sum += v[u].w;
  }
  sum = wave_sum(sum);
  if (lane == 0) red[wave] = sum;
  __syncthreads();
  sum = red[0] + red[1] + red[2] + red[3];
  const float inv = 1.f / sum;           // sum >= 1 (diag term is exp(0))

  const int dt_end = ((i >> 7) + 1) * 128;   // end of diagonal 128-tile
  #pragma unroll
  for (int u = 0; u < 2; ++u) {
    const int base = (t + u * 256) * 4;
    float4 w;
    w.x = v[u].x * inv; w.y = v[u].y * inv;
    w.z = v[u].z * inv; w.w = v[u].w * inv;
    *(float4*)(s + base) = w;            // f32 attn weights (0 above diag)
    if (base < dt_end) {
      ushort4 pk;
      pk.x = f2b(w.x); pk.y = f2b(w.y); pk.z = f2b(w.z); pk.w = f2b(w.w);
      *(ushort4*)((unsigned short*)p + base) = pk;
    }
  }
}

// ---- Stage D: O = P Vt^T (causal K-truncation) ---------------------------
// Linear grid 512, XCD-aware: all 8 dt of one (b,qt) share an XCD (P-strip
// L2 reuse); heavy-qt groups first.
__global__ __launch_bounds__(256, 4)
void out_kernel(const bf16* __restrict__ P, const bf16* __restrict__ Vt,
                float* __restrict__ O)
{
  const int L = blockIdx.x;               // 0..511
  const int x = L & 7;                    // XCD
  const int s = L >> 3;                   // 0..63
  const int dt  = s & 7;
  const int qtb = ((s >> 3) << 3) | x;    // 0..63, fixed XCD per (b,qt)
  const int qt  = 15 - (qtb >> 2);        // heavy-first (large qt at low L)
  const int b   = qtb & 3;

  __shared__ __align__(16) bf16 As[BM * BK];
  __shared__ __align__(16) bf16 Bs[BN * BK];

  f32x4 acc[4][4];
  zero_acc(acc);
  const int ksteps = (qt + 1) * (128 / BK);   // only k <= q-block end nonzero
  gemm_core<false>(P + (size_t)b * SS_ELEMS + (size_t)qt * 128 * S,
                   Vt + (size_t)b * D * S + (size_t)dt * 128 * S,
                   S, S, ksteps, As, Bs, acc);

  const int lane = threadIdx.x & 63, wave = threadIdx.x >> 6;
  const int wm = (wave & 1) * 64, wn = (wave >> 1) * 64;
  const int col0 = lane & 15, row0 = (lane >> 4) * 4;
  #pragma unroll
  for (int mi = 0; mi < 4; ++mi)
    #pragma unroll
    for (int ni = 0; ni < 4; ++ni)
      #pragma unroll
      for (int r = 0; r < 4; ++r) {
        const int gq = qt * 128 + wm + mi * 16 + row0 + r;
        const int gd = dt * 128 + wn + ni * 16 + col0;
        O[((size_t)b * S + gq) * D + gd] = acc[mi][ni][r];
      }
}

extern "C" void kernel_launch(void* const* d_in, const int* in_sizes, int n_in,
                              void* d_out, int out_size, void* d_ws, size_t ws_size,
                              hipStream_t stream) {
  const float* X  = (const float*)d_in[0];
  // d_in[1] = causal mask (int32 tril) — applied analytically, not read.
  const float* Wq = (const float*)d_in[2];
  const float* Wk = (const float*)d_in[3];
  const float* Wv = (const float*)d_in[4];

  float* Out  = (float*)d_out;               // (4,2048,1024) f32
  float* Attn = Out + QK_ELEMS;              // (4,2048,2048) f32

  bf16* Q   = (bf16*)d_ws;                   // 16MB
  bf16* K   = Q + QK_ELEMS;                  // 16MB
  bf16* Vt  = K + QK_ELEMS;                  // 16MB
  bf16* Xb  = Vt + QK_ELEMS;                 // 16MB
  bf16* Wqb = Xb + QK_ELEMS;                 // 2MB
  bf16* Wkb = Wqb + W_ELEMS;                 // 2MB
  bf16* Wvb = Wkb + W_ELEMS;                 // 2MB  -> ws total 70MB
  bf16* Pb  = (bf16*)d_ws;                   // 32MB, aliases Q+K (dead by then)

  const int cvt_blocks = (int)((QK_ELEMS + 3 * W_ELEMS) / 4 / 256);
  cvt_kernel<<<cvt_blocks, 256, 0, stream>>>(X, Wq, Wk, Wv, Xb, Wqb, Wkb, Wvb);
  qkv_kernel<<<dim3(1536), 256, 0, stream>>>(Xb, Wqb, Wkb, Wvb, Q, K, Vt);
  const int ntile = (S / 128) * (S / 128 + 1) / 2;   // 136
  scores_kernel<<<dim3(ntile, Bb), 256, 0, stream>>>(Q, K, Attn);
  softmax_kernel<<<dim3(Bb * S), 256, 0, stream>>>(Attn, Pb);
  out_kernel<<<dim3(512), 256, 0, stream>>>(Pb, Vt, Out);
}